// Round 18
// baseline (526.030 us; speedup 1.0000x reference)
//
#include <hip/hip_runtime.h>
#include <math.h>

// Llama4 experts + shared LoRA (rank 8) — bf16 MFMA GEMMs.
// E=8, T=1024, H=1024, I=2048, F2=4096, R=8, scaling=2.
//
// R17->R18: fix R17's staging-coverage bug (stage() issued 4 loads/thread
// covering only rows 0-31/64-95 of each 128-row panel -> rows 32-63/96-127
// stayed 0xAA-poisoned -> NaN). Full coverage = 8 loads/thread:
// l in 0..3: i=tid+l*256, r=i>>3 (0..127), sl=i&7; 1 A-load + 1 B-load.
// Structure unchanged from R17: single-buffer 32KB LDS m97 2-barrier loop,
// compiler-inserted waits, __launch_bounds__(256,3) -> 3 blk/CU = 12
// waves/CU; 128x128 tile, BK=64, XOR slot-swizzle both-sides, XCD-colocate
// block swizzle, f2bf pre-passes, LoRA/SwiGLU epilogues.

#define NE 8
#define TT 1024
#define HH 1024
#define II 2048
#define FF2 4096
#define RR 8
#define NROW (NE * TT)
#define SCAL 2.0f

typedef __bf16 bf16x8 __attribute__((ext_vector_type(8)));
typedef float f32x4 __attribute__((ext_vector_type(4)));

#define GLOAD16(g, l)                                                        \
  __builtin_amdgcn_global_load_lds((const __attribute__((address_space(1))) void*)(g), \
                                   (__attribute__((address_space(3))) void*)(l), 16, 0, 0)

__device__ __forceinline__ unsigned short f2bf(float f) {
  unsigned int u = __float_as_uint(f);
  u += 0x7fffu + ((u >> 16) & 1u);  // RNE
  return (unsigned short)(u >> 16);
}
__device__ __forceinline__ float dot4(float4 a, float4 b) {
  return a.x * b.x + a.y * b.y + a.z * b.z + a.w * b.w;
}

// ---------------- conversion pre-passes -------------------------------------
__global__ __launch_bounds__(256) void convx_kernel(const float* __restrict__ x,
                                                    unsigned short* __restrict__ xb) {
  const int i = blockIdx.x * 256 + threadIdx.x;
  const float4 a = *(const float4*)(x + (size_t)i * 8);
  const float4 b = *(const float4*)(x + (size_t)i * 8 + 4);
  union { unsigned short u[8]; uint4 v; } pk;
  pk.u[0] = f2bf(a.x); pk.u[1] = f2bf(a.y); pk.u[2] = f2bf(a.z); pk.u[3] = f2bf(a.w);
  pk.u[4] = f2bf(b.x); pk.u[5] = f2bf(b.y); pk.u[6] = f2bf(b.z); pk.u[7] = f2bf(b.w);
  *(uint4*)(xb + (size_t)i * 8) = pk.v;
}

// Wgu [e][1024][4096] f32 -> WguT [e][4096][1024] bf16, 16-granular interleave:
// gate col gc -> row (gc>>4)*32 + (gc&15); up col uc -> row (uc>>4)*32+16+(uc&15).
__global__ __launch_bounds__(256) void transconv_gu_kernel(const float* __restrict__ W,
                                                           unsigned short* __restrict__ WT) {
  __shared__ float ts[64][65];
  const int bid = blockIdx.x;           // 8*16*64
  const int nt = bid & 63, kt = (bid >> 6) & 15, e = bid >> 10;
  const float* Win = W + (size_t)e * HH * FF2 + (size_t)(kt * 64) * FF2 + nt * 64;
  const int tid = threadIdx.x;
#pragma unroll
  for (int l = 0; l < 4; ++l) {
    const int idx = tid + l * 256, r = idx >> 4, c4 = idx & 15;
    const float4 v = *(const float4*)(Win + (size_t)r * FF2 + c4 * 4);
    ts[r][c4 * 4 + 0] = v.x; ts[r][c4 * 4 + 1] = v.y;
    ts[r][c4 * 4 + 2] = v.z; ts[r][c4 * 4 + 3] = v.w;
  }
  __syncthreads();
  unsigned short* We = WT + (size_t)e * FF2 * HH;
#pragma unroll
  for (int l = 0; l < 2; ++l) {
    const int idx = tid + l * 256, j = idx >> 3, q = idx & 7;
    int orow;
    if (nt < 32) orow = (nt * 4 + (j >> 4)) * 32 + (j & 15);             // gate
    else         orow = ((nt - 32) * 4 + (j >> 4)) * 32 + 16 + (j & 15); // up
    union { unsigned short u[8]; uint4 v; } pk;
#pragma unroll
    for (int kk = 0; kk < 8; ++kk) pk.u[kk] = f2bf(ts[q * 8 + kk][j]);
    *(uint4*)(We + (size_t)orow * HH + kt * 64 + q * 8) = pk.v;
  }
}

// Wdn [e][2048][1024] f32 -> WdnT [e][1024][2048] bf16 (plain transpose).
__global__ __launch_bounds__(256) void transconv_dn_kernel(const float* __restrict__ W,
                                                           unsigned short* __restrict__ WT) {
  __shared__ float ts[64][65];
  const int bid = blockIdx.x;           // 8*32*16
  const int nt = bid & 15, kt = (bid >> 4) & 31, e = bid >> 9;
  const float* Win = W + (size_t)e * II * HH + (size_t)(kt * 64) * HH + nt * 64;
  const int tid = threadIdx.x;
#pragma unroll
  for (int l = 0; l < 4; ++l) {
    const int idx = tid + l * 256, r = idx >> 4, c4 = idx & 15;
    const float4 v = *(const float4*)(Win + (size_t)r * HH + c4 * 4);
    ts[r][c4 * 4 + 0] = v.x; ts[r][c4 * 4 + 1] = v.y;
    ts[r][c4 * 4 + 2] = v.z; ts[r][c4 * 4 + 3] = v.w;
  }
  __syncthreads();
  unsigned short* Wout = WT + (size_t)e * HH * II + (size_t)(nt * 64) * II + kt * 64;
#pragma unroll
  for (int l = 0; l < 2; ++l) {
    const int idx = tid + l * 256, j = idx >> 3, q = idx & 7;
    union { unsigned short u[8]; uint4 v; } pk;
#pragma unroll
    for (int kk = 0; kk < 8; ++kk) pk.u[kk] = f2bf(ts[q * 8 + kk][j]);
    *(uint4*)(Wout + (size_t)j * II + q * 8) = pk.v;
  }
}

// ---------------- rank-8 row dots -------------------------------------------
template <int K>
__global__ __launch_bounds__(256) void rowdot_kernel(const float* __restrict__ x,
                                                     const float* __restrict__ A,
                                                     float* __restrict__ xa) {
  const int w = threadIdx.x >> 6, lane = threadIdx.x & 63;
  const int t = blockIdx.x * 4 + w;
  const float* xrow = x + (size_t)t * K;
  float acc[RR];
#pragma unroll
  for (int r = 0; r < RR; ++r) acc[r] = 0.f;
#pragma unroll
  for (int c = 0; c < K / 256; ++c) {
    const float4 xv = *(const float4*)(xrow + c * 256 + lane * 4);
#pragma unroll
    for (int r = 0; r < RR; ++r) {
      const float4 av = *(const float4*)(A + (size_t)r * K + c * 256 + lane * 4);
      acc[r] += dot4(xv, av);
    }
  }
#pragma unroll
  for (int r = 0; r < RR; ++r) {
    float v = acc[r];
#pragma unroll
    for (int off = 32; off > 0; off >>= 1) v += __shfl_down(v, off, 64);
    if (lane == 0) xa[(size_t)t * RR + r] = v;
  }
}

__global__ __launch_bounds__(256) void rowdot_bf16_kernel(const unsigned short* __restrict__ h,
                                                          const float* __restrict__ A,
                                                          float* __restrict__ ha) {
  const int w = threadIdx.x >> 6, lane = threadIdx.x & 63;
  const int t = blockIdx.x * 4 + w;
  const unsigned short* hrow = h + (size_t)t * II;
  float acc[RR];
#pragma unroll
  for (int r = 0; r < RR; ++r) acc[r] = 0.f;
#pragma unroll
  for (int c = 0; c < II / 512; ++c) {
    const uint4 v = *(const uint4*)(hrow + c * 512 + lane * 8);
    float xv[8];
    xv[0] = __uint_as_float(v.x << 16); xv[1] = __uint_as_float(v.x & 0xffff0000u);
    xv[2] = __uint_as_float(v.y << 16); xv[3] = __uint_as_float(v.y & 0xffff0000u);
    xv[4] = __uint_as_float(v.z << 16); xv[5] = __uint_as_float(v.z & 0xffff0000u);
    xv[6] = __uint_as_float(v.w << 16); xv[7] = __uint_as_float(v.w & 0xffff0000u);
#pragma unroll
    for (int r = 0; r < RR; ++r) {
      const float4 a0 = *(const float4*)(A + (size_t)r * II + c * 512 + lane * 8);
      const float4 a1 = *(const float4*)(A + (size_t)r * II + c * 512 + lane * 8 + 4);
      acc[r] += xv[0] * a0.x + xv[1] * a0.y + xv[2] * a0.z + xv[3] * a0.w +
                xv[4] * a1.x + xv[5] * a1.y + xv[6] * a1.z + xv[7] * a1.w;
    }
  }
#pragma unroll
  for (int r = 0; r < RR; ++r) {
    float v = acc[r];
#pragma unroll
    for (int off = 32; off > 0; off >>= 1) v += __shfl_down(v, off, 64);
    if (lane == 0) ha[(size_t)t * RR + r] = v;
  }
}

// ---------------- gemm1: 128x128, BK=64, 4 waves, single-buffer m97 loop ----
// B panel = 128 WguT rows = 64 hidden cols (16-granular gate/up interleave).
// Wave wc owns B rows [wc*64, wc*64+64): n-frag parity = gate/up; pairs
// (2f,2f+1) share hidden-col block it*4 + wc*2 + f. acc[4][4]=64 f32/thread.
__global__ __launch_bounds__(256, 3) void gemm1_8p_kernel(
    const unsigned short* __restrict__ xb, const unsigned short* __restrict__ WguT,
    const float* __restrict__ xa, const float* __restrict__ Bgu,
    unsigned short* __restrict__ hidden) {
  __shared__ unsigned short sm[16384];  // A 128x64 @0, B 128x64 @byte16384; 32KB

  const int bid = blockIdx.x;          // 2048 = 8e * 8tt * 32it (swizzled)
  const int e = bid & 7;
  const int s = bid >> 3;              // 0..255
  const int g = s >> 6, wq = s & 63;   // groups of {8tt x 8it} = 4MB L2 set
  const int tt = wq >> 3, it = (g << 3) | (wq & 7);
  const int t0 = e * TT + tt * 128;
  const unsigned short* Ag = xb + (size_t)t0 * HH;
  const unsigned short* Bg = WguT + (size_t)e * FF2 * HH + (size_t)(it * 128) * HH;

  const int tid = threadIdx.x;
  const int w = tid >> 6, lane = tid & 63;
  const int wr = w >> 1, wc = w & 1;
  const int lrow = lane & 15, lkg = lane >> 4;

  // staging: 8 loads/thread covering both 128x64 panels (rows 0..127, 8 slots)
  auto stage = [&](int kt) {
#pragma unroll
    for (int l = 0; l < 4; ++l) {
      const int i = tid + l * 256;           // 0..1023
      const int r = i >> 3, sl = i & 7;      // r 0..127, sl 0..7
      const int off = kt * 64 + ((sl ^ (r & 7)) << 3);
      GLOAD16((const char*)(Ag + (size_t)r * HH + off),
              (char*)&sm[0] + r * 128 + sl * 16);
      GLOAD16((const char*)(Bg + (size_t)r * HH + off),
              (char*)&sm[0] + 16384 + r * 128 + sl * 16);
    }
  };
  auto ldA = [&](int mIdx, int s2) -> bf16x8 {
    const int row = wr * 64 + mIdx * 16 + lrow;
    const int sl = (s2 * 4 + lkg) ^ (row & 7);
    return *(const bf16x8*)((const char*)&sm[0] + row * 128 + sl * 16);
  };
  auto ldB = [&](int nj, int s2) -> bf16x8 {
    const int row = wc * 64 + nj * 16 + lrow;
    const int sl = (s2 * 4 + lkg) ^ (row & 7);
    return *(const bf16x8*)((const char*)&sm[0] + 16384 + row * 128 + sl * 16);
  };

  f32x4 acc[4][4];
#pragma unroll
  for (int i = 0; i < 4; ++i)
#pragma unroll
    for (int j = 0; j < 4; ++j) acc[i][j] = (f32x4)(0.f);

  const int NT = HH / 64;  // 16
  for (int t = 0; t < NT; ++t) {
    stage(t);
    __syncthreads();
    bf16x8 af[4][2], bfr[4][2];
#pragma unroll
    for (int mi = 0; mi < 4; ++mi) { af[mi][0] = ldA(mi, 0); af[mi][1] = ldA(mi, 1); }
#pragma unroll
    for (int nj = 0; nj < 4; ++nj) { bfr[nj][0] = ldB(nj, 0); bfr[nj][1] = ldB(nj, 1); }
#pragma unroll
    for (int mi = 0; mi < 4; ++mi)
#pragma unroll
      for (int nj = 0; nj < 4; ++nj)
#pragma unroll
        for (int s2 = 0; s2 < 2; ++s2)
          acc[mi][nj] = __builtin_amdgcn_mfma_f32_16x16x32_bf16(af[mi][s2], bfr[nj][s2], acc[mi][nj], 0, 0, 0);
    __syncthreads();
  }

  // epilogue: LoRA + SwiGLU, bf16 store. n-frag pairs (2f, 2f+1) = (gate, up)
  // for hidden col block it*4 + wc*2 + f.
  const float4* xa4 = (const float4*)xa;
  const float4* B4 = (const float4*)Bgu;
#pragma unroll
  for (int f = 0; f < 2; ++f) {
    const int gc = it * 64 + (wc * 2 + f) * 16 + lrow;
    const float4 bg0 = B4[gc * 2], bg1 = B4[gc * 2 + 1];
    const float4 bu0 = B4[(II + gc) * 2], bu1 = B4[(II + gc) * 2 + 1];
#pragma unroll
    for (int m = 0; m < 4; ++m) {
      const int tb = t0 + wr * 64 + m * 16 + lkg * 4;
#pragma unroll
      for (int j = 0; j < 4; ++j) {
        const int trow = tb + j;
        const float4 xr0 = xa4[trow * 2], xr1 = xa4[trow * 2 + 1];
        const float gv = acc[m][f * 2 + 0][j] + SCAL * (dot4(xr0, bg0) + dot4(xr1, bg1));
        const float uv = acc[m][f * 2 + 1][j] + SCAL * (dot4(xr0, bu0) + dot4(xr1, bu1));
        const float sg = gv / (1.f + __expf(-gv));
        hidden[(size_t)trow * II + gc] = f2bf(uv * sg);
      }
    }
  }
}

// ---------------- gemm2: 128x128, BK=64, 4 waves, single-buffer m97 loop ----
__global__ __launch_bounds__(256, 3) void gemm2_8p_kernel(
    const unsigned short* __restrict__ hid, const unsigned short* __restrict__ WdnT,
    const float* __restrict__ ha, const float* __restrict__ Bdn,
    float* __restrict__ out) {
  __shared__ unsigned short sm[16384];  // A 128x64 @0, B 128x64 @byte16384; 32KB

  const int bid = blockIdx.x;          // 512 = 8e * 8tt * 8ht (swizzled)
  const int e = bid & 7;
  const int s = bid >> 3;              // 0..63
  const int g = s >> 4, wq = s & 15;   // groups of {4tt x 4ht} = 4MB L2 set
  const int tt = (g >> 1) * 4 + (wq >> 2);
  const int ht = (g & 1) * 4 + (wq & 3);
  const int t0 = e * TT + tt * 128;
  const int h0 = ht * 128;
  const unsigned short* Ag = hid + (size_t)t0 * II;
  const unsigned short* Bg = WdnT + (size_t)e * HH * II + (size_t)h0 * II;

  const int tid = threadIdx.x;
  const int w = tid >> 6, lane = tid & 63;
  const int wr = w >> 1, wc = w & 1;
  const int lrow = lane & 15, lkg = lane >> 4;

  auto stage = [&](int kt) {
#pragma unroll
    for (int l = 0; l < 4; ++l) {
      const int i = tid + l * 256;
      const int r = i >> 3, sl = i & 7;
      const int off = kt * 64 + ((sl ^ (r & 7)) << 3);
      GLOAD16((const char*)(Ag + (size_t)r * II + off),
              (char*)&sm[0] + r * 128 + sl * 16);
      GLOAD16((const char*)(Bg + (size_t)r * II + off),
              (char*)&sm[0] + 16384 + r * 128 + sl * 16);
    }
  };
  auto ldA = [&](int mIdx, int s2) -> bf16x8 {
    const int row = wr * 64 + mIdx * 16 + lrow;
    const int sl = (s2 * 4 + lkg) ^ (row & 7);
    return *(const bf16x8*)((const char*)&sm[0] + row * 128 + sl * 16);
  };
  auto ldB = [&](int nj, int s2) -> bf16x8 {
    const int row = wc * 64 + nj * 16 + lrow;
    const int sl = (s2 * 4 + lkg) ^ (row & 7);
    return *(const bf16x8*)((const char*)&sm[0] + 16384 + row * 128 + sl * 16);
  };

  f32x4 acc[4][4];
#pragma unroll
  for (int i = 0; i < 4; ++i)
#pragma unroll
    for (int j = 0; j < 4; ++j) acc[i][j] = (f32x4)(0.f);

  const int NT = II / 64;  // 32
  for (int t = 0; t < NT; ++t) {
    stage(t);
    __syncthreads();
    bf16x8 af[4][2], bfr[4][2];
#pragma unroll
    for (int mi = 0; mi < 4; ++mi) { af[mi][0] = ldA(mi, 0); af[mi][1] = ldA(mi, 1); }
#pragma unroll
    for (int nj = 0; nj < 4; ++nj) { bfr[nj][0] = ldB(nj, 0); bfr[nj][1] = ldB(nj, 1); }
#pragma unroll
    for (int mi = 0; mi < 4; ++mi)
#pragma unroll
      for (int nj = 0; nj < 4; ++nj)
#pragma unroll
        for (int s2 = 0; s2 < 2; ++s2)
          acc[mi][nj] = __builtin_amdgcn_mfma_f32_16x16x32_bf16(af[mi][s2], bfr[nj][s2], acc[mi][nj], 0, 0, 0);
    __syncthreads();
  }

  const float4* ha4 = (const float4*)ha;
  const float4* B4 = (const float4*)Bdn;
#pragma unroll
  for (int nj = 0; nj < 4; ++nj) {
    const int col = h0 + wc * 64 + nj * 16 + lrow;
    const float4 b0 = B4[col * 2], b1 = B4[col * 2 + 1];
#pragma unroll
    for (int m = 0; m < 4; ++m) {
      const int tb = t0 + wr * 64 + m * 16 + lkg * 4;
#pragma unroll
      for (int j = 0; j < 4; ++j) {
        const int trow = tb + j;
        const float4 hr0 = ha4[trow * 2], hr1 = ha4[trow * 2 + 1];
        out[(size_t)trow * HH + col] = acc[m][nj][j] + SCAL * (dot4(hr0, b0) + dot4(hr1, b1));
      }
    }
  }
}

// ---------------- fallback (R3): in-loop conversion GEMMs -------------------
__global__ __launch_bounds__(256) void gemm1_conv_kernel(const float* __restrict__ x,
                                                         const float* __restrict__ Wgu,
                                                         const float* __restrict__ xa,
                                                         const float* __restrict__ Bgu,
                                                         unsigned short* __restrict__ hidden) {
  __shared__ unsigned short As[128][40];
  __shared__ unsigned short Bs[128][40];
  const int bid = blockIdx.x;
  const int e = bid >> 8, rem = bid & 255, tt = rem >> 5, it = rem & 31;
  const int t0 = e * TT + tt * 128, i0 = it * 64;
  const float* Wg = Wgu + (size_t)e * HH * FF2;
  const int tid = threadIdx.x, w = tid >> 6, lane = tid & 63;
  const int wr = w >> 1, wc = w & 1, lrow = lane & 15, lk = (lane >> 4) * 8;
  f32x4 acc[4][4];
#pragma unroll
  for (int i = 0; i < 4; ++i)
#pragma unroll
    for (int j = 0; j < 4; ++j) acc[i][j] = (f32x4)(0.f);
  for (int k0 = 0; k0 < HH; k0 += 32) {
#pragma unroll
    for (int l = 0; l < 4; ++l) {
      const int idx = tid + l * 256, row = idx >> 3, kq = idx & 7;
      const float4 v = *(const float4*)(x + (size_t)(t0 + row) * HH + k0 + kq * 4);
      ushort4 p; p.x = f2bf(v.x); p.y = f2bf(v.y); p.z = f2bf(v.z); p.w = f2bf(v.w);
      *(ushort4*)&As[row][kq * 4] = p;
    }
#pragma unroll
    for (int l = 0; l < 2; ++l) {
      const int idx = tid + l * 256, col = idx & 127, kq8 = idx >> 7;
      const int gcol = i0 + (col & 63) + ((col >> 6) * II);
      union { unsigned short u[8]; uint4 v; } pk;
#pragma unroll
      for (int kk = 0; kk < 8; ++kk) pk.u[kk] = f2bf(Wg[(size_t)(k0 + kq8 * 8 + kk) * FF2 + gcol]);
      *(uint4*)&Bs[col][kq8 * 8] = pk.v;
    }
    __syncthreads();
    bf16x8 af[4], bfr[4];
#pragma unroll
    for (int mi = 0; mi < 4; ++mi) af[mi] = *(const bf16x8*)&As[wr * 64 + mi * 16 + lrow][lk];
#pragma unroll
    for (int nj = 0; nj < 4; ++nj) {
      const int c = (nj < 2) ? (wc * 32 + nj * 16) : (64 + wc * 32 + (nj - 2) * 16);
      bfr[nj] = *(const bf16x8*)&Bs[c + lrow][lk];
    }
#pragma unroll
    for (int mi = 0; mi < 4; ++mi)
#pragma unroll
      for (int nj = 0; nj < 4; ++nj)
        acc[mi][nj] = __builtin_amdgcn_mfma_f32_16x16x32_bf16(af[mi], bfr[nj], acc[mi][nj], 0, 0, 0);
    __syncthreads();
  }
  const float4* xa4 = (const float4*)xa;
  const float4* B4 = (const float4*)Bgu;
#pragma unroll
  for (int nj = 0; nj < 2; ++nj) {
    const int coln = i0 + wc * 32 + nj * 16 + lrow;
    const float4 bg0 = B4[coln * 2], bg1 = B4[coln * 2 + 1];
    const float4 bu0 = B4[(II + coln) * 2], bu1 = B4[(II + coln) * 2 + 1];
#pragma unroll
    for (int mi = 0; mi < 4; ++mi) {
      const int tb = t0 + wr * 64 + mi * 16 + (lane >> 4) * 4;
#pragma unroll
      for (int j = 0; j < 4; ++j) {
        const int t = tb + j;
        const float4 xr0 = xa4[t * 2], xr1 = xa4[t * 2 + 1];
        const float g = acc[mi][nj][j] + SCAL * (dot4(xr0, bg0) + dot4(xr1, bg1));
        const float u = acc[mi][nj + 2][j] + SCAL * (dot4(xr0, bu0) + dot4(xr1, bu1));
        const float s = g / (1.f + __expf(-g));
        hidden[(size_t)t * II + coln] = f2bf(u * s);
      }
    }
  }
}

__global__ __launch_bounds__(256) void gemm2_conv_kernel(const unsigned short* __restrict__ hid,
                                                         const float* __restrict__ Wdn,
                                                         const float* __restrict__ ha,
                                                         const float* __restrict__ Bdn,
                                                         float* __restrict__ out) {
  __shared__ unsigned short As[128][40];
  __shared__ unsigned short Bs[128][40];
  const int bid = blockIdx.x;
  const int e = bid >> 6, rem = bid & 63, tt = rem >> 3, ht = rem & 7;
  const int t0 = e * TT + tt * 128, h0 = ht * 128;
  const float* Wd = Wdn + (size_t)e * II * HH;
  const int tid = threadIdx.x, w = tid >> 6, lane = tid & 63;
  const int wr = w >> 1, wc = w & 1, lrow = lane & 15, lk = (lane >> 4) * 8;
  f32x4 acc[4][4];
#pragma unroll
  for (int i = 0; i < 4; ++i)
#pragma unroll
    for (int j = 0; j < 4; ++j) acc[i][j] = (f32x4)(0.f);
  for (int k0 = 0; k0 < II; k0 += 32) {
#pragma unroll
    for (int l = 0; l < 2; ++l) {
      const int idx = tid + l * 256, row = idx >> 2, kq8 = idx & 3;
      *(uint4*)&As[row][kq8 * 8] = *(const uint4*)(hid + (size_t)(t0 + row) * II + k0 + kq8 * 8);
    }
#pragma unroll
    for (int l = 0; l < 2; ++l) {
      const int idx = tid + l * 256, col = idx & 127, kq8 = idx >> 7;
      union { unsigned short u[8]; uint4 v; } pk;
#pragma unroll
      for (int kk = 0; kk < 8; ++kk) pk.u[kk] = f2bf(Wd[(size_t)(k0 + kq8 * 8 + kk) * HH + h0 + col]);
      *(uint4*)&Bs[col][kq8 * 8] = pk.v;
    }
    __syncthreads();
    bf16x8 af[4], bfr[4];
#pragma unroll
    for (int mi = 0; mi < 4; ++mi) af[mi] = *(const bf16x8*)&As[wr * 64 + mi * 16 + lrow][lk];
#pragma unroll
    for (int nj = 0; nj < 4; ++nj) bfr[nj] = *(const bf16x8*)&Bs[wc * 64 + nj * 16 + lrow][lk];
#pragma unroll
    for (int mi = 0; mi < 4; ++mi)
#pragma unroll
      for (int nj = 0; nj < 4; ++nj)
        acc[mi][nj] = __builtin_amdgcn_mfma_f32_16x16x32_bf16(af[mi], bfr[nj], acc[mi][nj], 0, 0, 0);
    __syncthreads();
  }
  const float4* ha4 = (const float4*)ha;
  const float4* B4 = (const float4*)Bdn;
#pragma unroll
  for (int nj = 0; nj < 4; ++nj) {
    const int coln = h0 + wc * 64 + nj * 16 + lrow;
    const float4 b0 = B4[coln * 2], b1 = B4[coln * 2 + 1];
#pragma unroll
    for (int mi = 0; mi < 4; ++mi) {
      const int tb = t0 + wr * 64 + mi * 16 + (lane >> 4) * 4;
#pragma unroll
      for (int j = 0; j < 4; ++j) {
        const int t = tb + j;
        const float4 hr0 = ha4[t * 2], hr1 = ha4[t * 2 + 1];
        out[(size_t)t * HH + coln] = acc[mi][nj][j] + SCAL * (dot4(hr0, b0) + dot4(hr1, b1));
      }
    }
  }
}

extern "C" void kernel_launch(void* const* d_in, const int* in_sizes, int n_in,
                              void* d_out, int out_size, void* d_ws, size_t ws_size,
                              hipStream_t stream) {
  const float* x   = (const float*)d_in[0];
  const float* Wgu = (const float*)d_in[1];
  const float* Wdn = (const float*)d_in[2];
  const float* Agu = (const float*)d_in[3];
  const float* Bgu = (const float*)d_in[4];
  const float* Adn = (const float*)d_in[5];
  const float* Bdn = (const float*)d_in[6];
  float* out = (float*)d_out;

  char* ws = (char*)d_ws;
  unsigned short* hidden = (unsigned short*)ws;                      //  32 MB
  const size_t OFF_XB  = (size_t)NROW * II * 2;                      //  32 MB
  const size_t OFF_WGU = OFF_XB + (size_t)NROW * HH * 2;             //  48 MB
  const size_t OFF_WDN = OFF_WGU + (size_t)NE * FF2 * HH * 2;        // 112 MB
  const size_t OFF_XA  = OFF_WDN + (size_t)NE * HH * II * 2;         // 144 MB
  const size_t OFF_HA  = OFF_XA + (size_t)NROW * RR * 4;
  const size_t NEED    = OFF_HA + (size_t)NROW * RR * 4;

  if (ws_size >= NEED) {
    unsigned short* xb   = (unsigned short*)(ws + OFF_XB);
    unsigned short* WguT = (unsigned short*)(ws + OFF_WGU);
    unsigned short* WdnT = (unsigned short*)(ws + OFF_WDN);
    float* xa = (float*)(ws + OFF_XA);
    float* ha = (float*)(ws + OFF_HA);

    convx_kernel<<<(NROW * HH) / (256 * 8), 256, 0, stream>>>(x, xb);
    transconv_gu_kernel<<<NE * 16 * 64, 256, 0, stream>>>(Wgu, WguT);
    transconv_dn_kernel<<<NE * 32 * 16, 256, 0, stream>>>(Wdn, WdnT);
    rowdot_kernel<HH><<<NROW / 4, 256, 0, stream>>>(x, Agu, xa);
    gemm1_8p_kernel<<<NE * 8 * 32, 256, 0, stream>>>(xb, WguT, xa, Bgu, hidden);
    rowdot_bf16_kernel<<<NROW / 4, 256, 0, stream>>>(hidden, Adn, ha);
    gemm2_8p_kernel<<<NE * 8 * 8, 256, 0, stream>>>(hidden, WdnT, ha, Bdn, out);
  } else {
    float* xa = (float*)(ws + OFF_XB);
    float* ha = xa + (size_t)NROW * RR;
    rowdot_kernel<HH><<<NROW / 4, 256, 0, stream>>>(x, Agu, xa);
    gemm1_conv_kernel<<<NE * 8 * 32, 256, 0, stream>>>(x, Wgu, xa, Bgu, hidden);
    rowdot_bf16_kernel<<<NROW / 4, 256, 0, stream>>>(hidden, Adn, ha);
    gemm2_conv_kernel<<<NE * 8 * 8, 256, 0, stream>>>(hidden, Wdn, ha, Bdn, out);
  }
}

// Round 19
// 435.265 us; speedup vs baseline: 1.2085x; 1.2085x over previous
//
#include <hip/hip_runtime.h>
#include <math.h>

// Llama4 experts + shared LoRA (rank 8) — bf16 MFMA GEMMs.
// E=8, T=1024, H=1024, I=2048, F2=4096, R=8, scaling=2.
//
// R18->R19: (256,3) produced an 84-VGPR cap (toolchain's 2nd launch_bounds
// arg is unpredictable: (512,2)/(512)/(512,1)->128, (256,3)->84) -> massive
// spill (WRITE 398MB). New approach: NO 2nd arg; lower natural register
// pressure instead. Split the MFMA loop by k-slice s2: load 8 frags (16
// VGPR) -> 16 MFMA -> next slice. Frag liveness 32->16 regs; natural alloc
// was 172 (2 over the 170 threshold for 3 waves/SIMD) -> expect ~150-165 ->
// allocator can pick 3 waves/SIMD naturally (32KB LDS allows 5 blk/CU).
// Unchanged from R18: single-buffer m97 2-barrier loop, 128x128 tile, BK=64,
// XOR slot-swizzle both-sides, XCD-colocate, f2bf pre-passes, epilogues.

#define NE 8
#define TT 1024
#define HH 1024
#define II 2048
#define FF2 4096
#define RR 8
#define NROW (NE * TT)
#define SCAL 2.0f

typedef __bf16 bf16x8 __attribute__((ext_vector_type(8)));
typedef float f32x4 __attribute__((ext_vector_type(4)));

#define GLOAD16(g, l)                                                        \
  __builtin_amdgcn_global_load_lds((const __attribute__((address_space(1))) void*)(g), \
                                   (__attribute__((address_space(3))) void*)(l), 16, 0, 0)

__device__ __forceinline__ unsigned short f2bf(float f) {
  unsigned int u = __float_as_uint(f);
  u += 0x7fffu + ((u >> 16) & 1u);  // RNE
  return (unsigned short)(u >> 16);
}
__device__ __forceinline__ float dot4(float4 a, float4 b) {
  return a.x * b.x + a.y * b.y + a.z * b.z + a.w * b.w;
}

// ---------------- conversion pre-passes -------------------------------------
__global__ __launch_bounds__(256) void convx_kernel(const float* __restrict__ x,
                                                    unsigned short* __restrict__ xb) {
  const int i = blockIdx.x * 256 + threadIdx.x;
  const float4 a = *(const float4*)(x + (size_t)i * 8);
  const float4 b = *(const float4*)(x + (size_t)i * 8 + 4);
  union { unsigned short u[8]; uint4 v; } pk;
  pk.u[0] = f2bf(a.x); pk.u[1] = f2bf(a.y); pk.u[2] = f2bf(a.z); pk.u[3] = f2bf(a.w);
  pk.u[4] = f2bf(b.x); pk.u[5] = f2bf(b.y); pk.u[6] = f2bf(b.z); pk.u[7] = f2bf(b.w);
  *(uint4*)(xb + (size_t)i * 8) = pk.v;
}

// Wgu [e][1024][4096] f32 -> WguT [e][4096][1024] bf16, 16-granular interleave:
// gate col gc -> row (gc>>4)*32 + (gc&15); up col uc -> row (uc>>4)*32+16+(uc&15).
__global__ __launch_bounds__(256) void transconv_gu_kernel(const float* __restrict__ W,
                                                           unsigned short* __restrict__ WT) {
  __shared__ float ts[64][65];
  const int bid = blockIdx.x;           // 8*16*64
  const int nt = bid & 63, kt = (bid >> 6) & 15, e = bid >> 10;
  const float* Win = W + (size_t)e * HH * FF2 + (size_t)(kt * 64) * FF2 + nt * 64;
  const int tid = threadIdx.x;
#pragma unroll
  for (int l = 0; l < 4; ++l) {
    const int idx = tid + l * 256, r = idx >> 4, c4 = idx & 15;
    const float4 v = *(const float4*)(Win + (size_t)r * FF2 + c4 * 4);
    ts[r][c4 * 4 + 0] = v.x; ts[r][c4 * 4 + 1] = v.y;
    ts[r][c4 * 4 + 2] = v.z; ts[r][c4 * 4 + 3] = v.w;
  }
  __syncthreads();
  unsigned short* We = WT + (size_t)e * FF2 * HH;
#pragma unroll
  for (int l = 0; l < 2; ++l) {
    const int idx = tid + l * 256, j = idx >> 3, q = idx & 7;
    int orow;
    if (nt < 32) orow = (nt * 4 + (j >> 4)) * 32 + (j & 15);             // gate
    else         orow = ((nt - 32) * 4 + (j >> 4)) * 32 + 16 + (j & 15); // up
    union { unsigned short u[8]; uint4 v; } pk;
#pragma unroll
    for (int kk = 0; kk < 8; ++kk) pk.u[kk] = f2bf(ts[q * 8 + kk][j]);
    *(uint4*)(We + (size_t)orow * HH + kt * 64 + q * 8) = pk.v;
  }
}

// Wdn [e][2048][1024] f32 -> WdnT [e][1024][2048] bf16 (plain transpose).
__global__ __launch_bounds__(256) void transconv_dn_kernel(const float* __restrict__ W,
                                                           unsigned short* __restrict__ WT) {
  __shared__ float ts[64][65];
  const int bid = blockIdx.x;           // 8*32*16
  const int nt = bid & 15, kt = (bid >> 4) & 31, e = bid >> 9;
  const float* Win = W + (size_t)e * II * HH + (size_t)(kt * 64) * HH + nt * 64;
  const int tid = threadIdx.x;
#pragma unroll
  for (int l = 0; l < 4; ++l) {
    const int idx = tid + l * 256, r = idx >> 4, c4 = idx & 15;
    const float4 v = *(const float4*)(Win + (size_t)r * HH + c4 * 4);
    ts[r][c4 * 4 + 0] = v.x; ts[r][c4 * 4 + 1] = v.y;
    ts[r][c4 * 4 + 2] = v.z; ts[r][c4 * 4 + 3] = v.w;
  }
  __syncthreads();
  unsigned short* Wout = WT + (size_t)e * HH * II + (size_t)(nt * 64) * II + kt * 64;
#pragma unroll
  for (int l = 0; l < 2; ++l) {
    const int idx = tid + l * 256, j = idx >> 3, q = idx & 7;
    union { unsigned short u[8]; uint4 v; } pk;
#pragma unroll
    for (int kk = 0; kk < 8; ++kk) pk.u[kk] = f2bf(ts[q * 8 + kk][j]);
    *(uint4*)(Wout + (size_t)j * II + q * 8) = pk.v;
  }
}

// ---------------- rank-8 row dots -------------------------------------------
template <int K>
__global__ __launch_bounds__(256) void rowdot_kernel(const float* __restrict__ x,
                                                     const float* __restrict__ A,
                                                     float* __restrict__ xa) {
  const int w = threadIdx.x >> 6, lane = threadIdx.x & 63;
  const int t = blockIdx.x * 4 + w;
  const float* xrow = x + (size_t)t * K;
  float acc[RR];
#pragma unroll
  for (int r = 0; r < RR; ++r) acc[r] = 0.f;
#pragma unroll
  for (int c = 0; c < K / 256; ++c) {
    const float4 xv = *(const float4*)(xrow + c * 256 + lane * 4);
#pragma unroll
    for (int r = 0; r < RR; ++r) {
      const float4 av = *(const float4*)(A + (size_t)r * K + c * 256 + lane * 4);
      acc[r] += dot4(xv, av);
    }
  }
#pragma unroll
  for (int r = 0; r < RR; ++r) {
    float v = acc[r];
#pragma unroll
    for (int off = 32; off > 0; off >>= 1) v += __shfl_down(v, off, 64);
    if (lane == 0) xa[(size_t)t * RR + r] = v;
  }
}

__global__ __launch_bounds__(256) void rowdot_bf16_kernel(const unsigned short* __restrict__ h,
                                                          const float* __restrict__ A,
                                                          float* __restrict__ ha) {
  const int w = threadIdx.x >> 6, lane = threadIdx.x & 63;
  const int t = blockIdx.x * 4 + w;
  const unsigned short* hrow = h + (size_t)t * II;
  float acc[RR];
#pragma unroll
  for (int r = 0; r < RR; ++r) acc[r] = 0.f;
#pragma unroll
  for (int c = 0; c < II / 512; ++c) {
    const uint4 v = *(const uint4*)(hrow + c * 512 + lane * 8);
    float xv[8];
    xv[0] = __uint_as_float(v.x << 16); xv[1] = __uint_as_float(v.x & 0xffff0000u);
    xv[2] = __uint_as_float(v.y << 16); xv[3] = __uint_as_float(v.y & 0xffff0000u);
    xv[4] = __uint_as_float(v.z << 16); xv[5] = __uint_as_float(v.z & 0xffff0000u);
    xv[6] = __uint_as_float(v.w << 16); xv[7] = __uint_as_float(v.w & 0xffff0000u);
#pragma unroll
    for (int r = 0; r < RR; ++r) {
      const float4 a0 = *(const float4*)(A + (size_t)r * II + c * 512 + lane * 8);
      const float4 a1 = *(const float4*)(A + (size_t)r * II + c * 512 + lane * 8 + 4);
      acc[r] += xv[0] * a0.x + xv[1] * a0.y + xv[2] * a0.z + xv[3] * a0.w +
                xv[4] * a1.x + xv[5] * a1.y + xv[6] * a1.z + xv[7] * a1.w;
    }
  }
#pragma unroll
  for (int r = 0; r < RR; ++r) {
    float v = acc[r];
#pragma unroll
    for (int off = 32; off > 0; off >>= 1) v += __shfl_down(v, off, 64);
    if (lane == 0) ha[(size_t)t * RR + r] = v;
  }
}

// ---------------- gemm1: 128x128, BK=64, 4 waves, single-buffer, s2-split ---
// B panel = 128 WguT rows = 64 hidden cols (16-granular gate/up interleave).
// Wave wc owns B rows [wc*64, wc*64+64): n-frag parity = gate/up; pairs
// (2f,2f+1) share hidden-col block it*4 + wc*2 + f. acc[4][4]=64 f32/thread.
__global__ __launch_bounds__(256) void gemm1_8p_kernel(
    const unsigned short* __restrict__ xb, const unsigned short* __restrict__ WguT,
    const float* __restrict__ xa, const float* __restrict__ Bgu,
    unsigned short* __restrict__ hidden) {
  __shared__ unsigned short sm[16384];  // A 128x64 @0, B 128x64 @byte16384; 32KB

  const int bid = blockIdx.x;          // 2048 = 8e * 8tt * 32it (swizzled)
  const int e = bid & 7;
  const int s = bid >> 3;              // 0..255
  const int g = s >> 6, wq = s & 63;   // groups of {8tt x 8it} = 4MB L2 set
  const int tt = wq >> 3, it = (g << 3) | (wq & 7);
  const int t0 = e * TT + tt * 128;
  const unsigned short* Ag = xb + (size_t)t0 * HH;
  const unsigned short* Bg = WguT + (size_t)e * FF2 * HH + (size_t)(it * 128) * HH;

  const int tid = threadIdx.x;
  const int w = tid >> 6, lane = tid & 63;
  const int wr = w >> 1, wc = w & 1;
  const int lrow = lane & 15, lkg = lane >> 4;

  // staging: 8 loads/thread covering both 128x64 panels (rows 0..127, 8 slots)
  auto stage = [&](int kt) {
#pragma unroll
    for (int l = 0; l < 4; ++l) {
      const int i = tid + l * 256;           // 0..1023
      const int r = i >> 3, sl = i & 7;      // r 0..127, sl 0..7
      const int off = kt * 64 + ((sl ^ (r & 7)) << 3);
      GLOAD16((const char*)(Ag + (size_t)r * HH + off),
              (char*)&sm[0] + r * 128 + sl * 16);
      GLOAD16((const char*)(Bg + (size_t)r * HH + off),
              (char*)&sm[0] + 16384 + r * 128 + sl * 16);
    }
  };
  auto ldA = [&](int mIdx, int s2) -> bf16x8 {
    const int row = wr * 64 + mIdx * 16 + lrow;
    const int sl = (s2 * 4 + lkg) ^ (row & 7);
    return *(const bf16x8*)((const char*)&sm[0] + row * 128 + sl * 16);
  };
  auto ldB = [&](int nj, int s2) -> bf16x8 {
    const int row = wc * 64 + nj * 16 + lrow;
    const int sl = (s2 * 4 + lkg) ^ (row & 7);
    return *(const bf16x8*)((const char*)&sm[0] + 16384 + row * 128 + sl * 16);
  };

  f32x4 acc[4][4];
#pragma unroll
  for (int i = 0; i < 4; ++i)
#pragma unroll
    for (int j = 0; j < 4; ++j) acc[i][j] = (f32x4)(0.f);

  const int NT = HH / 64;  // 16
  for (int t = 0; t < NT; ++t) {
    stage(t);
    __syncthreads();
#pragma unroll
    for (int s2 = 0; s2 < 2; ++s2) {       // k-slice split: frag liveness 16 regs
      bf16x8 af[4], bfr[4];
#pragma unroll
      for (int mi = 0; mi < 4; ++mi) af[mi] = ldA(mi, s2);
#pragma unroll
      for (int nj = 0; nj < 4; ++nj) bfr[nj] = ldB(nj, s2);
#pragma unroll
      for (int mi = 0; mi < 4; ++mi)
#pragma unroll
        for (int nj = 0; nj < 4; ++nj)
          acc[mi][nj] = __builtin_amdgcn_mfma_f32_16x16x32_bf16(af[mi], bfr[nj], acc[mi][nj], 0, 0, 0);
    }
    __syncthreads();
  }

  // epilogue: LoRA + SwiGLU, bf16 store. n-frag pairs (2f, 2f+1) = (gate, up)
  // for hidden col block it*4 + wc*2 + f.
  const float4* xa4 = (const float4*)xa;
  const float4* B4 = (const float4*)Bgu;
#pragma unroll
  for (int f = 0; f < 2; ++f) {
    const int gc = it * 64 + (wc * 2 + f) * 16 + lrow;
    const float4 bg0 = B4[gc * 2], bg1 = B4[gc * 2 + 1];
    const float4 bu0 = B4[(II + gc) * 2], bu1 = B4[(II + gc) * 2 + 1];
#pragma unroll
    for (int m = 0; m < 4; ++m) {
      const int tb = t0 + wr * 64 + m * 16 + lkg * 4;
#pragma unroll
      for (int j = 0; j < 4; ++j) {
        const int trow = tb + j;
        const float4 xr0 = xa4[trow * 2], xr1 = xa4[trow * 2 + 1];
        const float gv = acc[m][f * 2 + 0][j] + SCAL * (dot4(xr0, bg0) + dot4(xr1, bg1));
        const float uv = acc[m][f * 2 + 1][j] + SCAL * (dot4(xr0, bu0) + dot4(xr1, bu1));
        const float sg = gv / (1.f + __expf(-gv));
        hidden[(size_t)trow * II + gc] = f2bf(uv * sg);
      }
    }
  }
}

// ---------------- gemm2: 128x128, BK=64, 4 waves, single-buffer, s2-split ---
__global__ __launch_bounds__(256) void gemm2_8p_kernel(
    const unsigned short* __restrict__ hid, const unsigned short* __restrict__ WdnT,
    const float* __restrict__ ha, const float* __restrict__ Bdn,
    float* __restrict__ out) {
  __shared__ unsigned short sm[16384];  // A 128x64 @0, B 128x64 @byte16384; 32KB

  const int bid = blockIdx.x;          // 512 = 8e * 8tt * 8ht (swizzled)
  const int e = bid & 7;
  const int s = bid >> 3;              // 0..63
  const int g = s >> 4, wq = s & 15;   // groups of {4tt x 4ht} = 4MB L2 set
  const int tt = (g >> 1) * 4 + (wq >> 2);
  const int ht = (g & 1) * 4 + (wq & 3);
  const int t0 = e * TT + tt * 128;
  const int h0 = ht * 128;
  const unsigned short* Ag = hid + (size_t)t0 * II;
  const unsigned short* Bg = WdnT + (size_t)e * HH * II + (size_t)h0 * II;

  const int tid = threadIdx.x;
  const int w = tid >> 6, lane = tid & 63;
  const int wr = w >> 1, wc = w & 1;
  const int lrow = lane & 15, lkg = lane >> 4;

  auto stage = [&](int kt) {
#pragma unroll
    for (int l = 0; l < 4; ++l) {
      const int i = tid + l * 256;
      const int r = i >> 3, sl = i & 7;
      const int off = kt * 64 + ((sl ^ (r & 7)) << 3);
      GLOAD16((const char*)(Ag + (size_t)r * II + off),
              (char*)&sm[0] + r * 128 + sl * 16);
      GLOAD16((const char*)(Bg + (size_t)r * II + off),
              (char*)&sm[0] + 16384 + r * 128 + sl * 16);
    }
  };
  auto ldA = [&](int mIdx, int s2) -> bf16x8 {
    const int row = wr * 64 + mIdx * 16 + lrow;
    const int sl = (s2 * 4 + lkg) ^ (row & 7);
    return *(const bf16x8*)((const char*)&sm[0] + row * 128 + sl * 16);
  };
  auto ldB = [&](int nj, int s2) -> bf16x8 {
    const int row = wc * 64 + nj * 16 + lrow;
    const int sl = (s2 * 4 + lkg) ^ (row & 7);
    return *(const bf16x8*)((const char*)&sm[0] + 16384 + row * 128 + sl * 16);
  };

  f32x4 acc[4][4];
#pragma unroll
  for (int i = 0; i < 4; ++i)
#pragma unroll
    for (int j = 0; j < 4; ++j) acc[i][j] = (f32x4)(0.f);

  const int NT = II / 64;  // 32
  for (int t = 0; t < NT; ++t) {
    stage(t);
    __syncthreads();
#pragma unroll
    for (int s2 = 0; s2 < 2; ++s2) {
      bf16x8 af[4], bfr[4];
#pragma unroll
      for (int mi = 0; mi < 4; ++mi) af[mi] = ldA(mi, s2);
#pragma unroll
      for (int nj = 0; nj < 4; ++nj) bfr[nj] = ldB(nj, s2);
#pragma unroll
      for (int mi = 0; mi < 4; ++mi)
#pragma unroll
        for (int nj = 0; nj < 4; ++nj)
          acc[mi][nj] = __builtin_amdgcn_mfma_f32_16x16x32_bf16(af[mi], bfr[nj], acc[mi][nj], 0, 0, 0);
    }
    __syncthreads();
  }

  const float4* ha4 = (const float4*)ha;
  const float4* B4 = (const float4*)Bdn;
#pragma unroll
  for (int nj = 0; nj < 4; ++nj) {
    const int col = h0 + wc * 64 + nj * 16 + lrow;
    const float4 b0 = B4[col * 2], b1 = B4[col * 2 + 1];
#pragma unroll
    for (int m = 0; m < 4; ++m) {
      const int tb = t0 + wr * 64 + m * 16 + lkg * 4;
#pragma unroll
      for (int j = 0; j < 4; ++j) {
        const int trow = tb + j;
        const float4 hr0 = ha4[trow * 2], hr1 = ha4[trow * 2 + 1];
        out[(size_t)trow * HH + col] = acc[m][nj][j] + SCAL * (dot4(hr0, b0) + dot4(hr1, b1));
      }
    }
  }
}

// ---------------- fallback (R3): in-loop conversion GEMMs -------------------
__global__ __launch_bounds__(256) void gemm1_conv_kernel(const float* __restrict__ x,
                                                         const float* __restrict__ Wgu,
                                                         const float* __restrict__ xa,
                                                         const float* __restrict__ Bgu,
                                                         unsigned short* __restrict__ hidden) {
  __shared__ unsigned short As[128][40];
  __shared__ unsigned short Bs[128][40];
  const int bid = blockIdx.x;
  const int e = bid >> 8, rem = bid & 255, tt = rem >> 5, it = rem & 31;
  const int t0 = e * TT + tt * 128, i0 = it * 64;
  const float* Wg = Wgu + (size_t)e * HH * FF2;
  const int tid = threadIdx.x, w = tid >> 6, lane = tid & 63;
  const int wr = w >> 1, wc = w & 1, lrow = lane & 15, lk = (lane >> 4) * 8;
  f32x4 acc[4][4];
#pragma unroll
  for (int i = 0; i < 4; ++i)
#pragma unroll
    for (int j = 0; j < 4; ++j) acc[i][j] = (f32x4)(0.f);
  for (int k0 = 0; k0 < HH; k0 += 32) {
#pragma unroll
    for (int l = 0; l < 4; ++l) {
      const int idx = tid + l * 256, row = idx >> 3, kq = idx & 7;
      const float4 v = *(const float4*)(x + (size_t)(t0 + row) * HH + k0 + kq * 4);
      ushort4 p; p.x = f2bf(v.x); p.y = f2bf(v.y); p.z = f2bf(v.z); p.w = f2bf(v.w);
      *(ushort4*)&As[row][kq * 4] = p;
    }
#pragma unroll
    for (int l = 0; l < 2; ++l) {
      const int idx = tid + l * 256, col = idx & 127, kq8 = idx >> 7;
      const int gcol = i0 + (col & 63) + ((col >> 6) * II);
      union { unsigned short u[8]; uint4 v; } pk;
#pragma unroll
      for (int kk = 0; kk < 8; ++kk) pk.u[kk] = f2bf(Wg[(size_t)(k0 + kq8 * 8 + kk) * FF2 + gcol]);
      *(uint4*)&Bs[col][kq8 * 8] = pk.v;
    }
    __syncthreads();
    bf16x8 af[4], bfr[4];
#pragma unroll
    for (int mi = 0; mi < 4; ++mi) af[mi] = *(const bf16x8*)&As[wr * 64 + mi * 16 + lrow][lk];
#pragma unroll
    for (int nj = 0; nj < 4; ++nj) {
      const int c = (nj < 2) ? (wc * 32 + nj * 16) : (64 + wc * 32 + (nj - 2) * 16);
      bfr[nj] = *(const bf16x8*)&Bs[c + lrow][lk];
    }
#pragma unroll
    for (int mi = 0; mi < 4; ++mi)
#pragma unroll
      for (int nj = 0; nj < 4; ++nj)
        acc[mi][nj] = __builtin_amdgcn_mfma_f32_16x16x32_bf16(af[mi], bfr[nj], acc[mi][nj], 0, 0, 0);
    __syncthreads();
  }
  const float4* xa4 = (const float4*)xa;
  const float4* B4 = (const float4*)Bgu;
#pragma unroll
  for (int nj = 0; nj < 2; ++nj) {
    const int coln = i0 + wc * 32 + nj * 16 + lrow;
    const float4 bg0 = B4[coln * 2], bg1 = B4[coln * 2 + 1];
    const float4 bu0 = B4[(II + coln) * 2], bu1 = B4[(II + coln) * 2 + 1];
#pragma unroll
    for (int mi = 0; mi < 4; ++mi) {
      const int tb = t0 + wr * 64 + mi * 16 + (lane >> 4) * 4;
#pragma unroll
      for (int j = 0; j < 4; ++j) {
        const int t = tb + j;
        const float4 xr0 = xa4[t * 2], xr1 = xa4[t * 2 + 1];
        const float g = acc[mi][nj][j] + SCAL * (dot4(xr0, bg0) + dot4(xr1, bg1));
        const float u = acc[mi][nj + 2][j] + SCAL * (dot4(xr0, bu0) + dot4(xr1, bu1));
        const float s = g / (1.f + __expf(-g));
        hidden[(size_t)t * II + coln] = f2bf(u * s);
      }
    }
  }
}

__global__ __launch_bounds__(256) void gemm2_conv_kernel(const unsigned short* __restrict__ hid,
                                                         const float* __restrict__ Wdn,
                                                         const float* __restrict__ ha,
                                                         const float* __restrict__ Bdn,
                                                         float* __restrict__ out) {
  __shared__ unsigned short As[128][40];
  __shared__ unsigned short Bs[128][40];
  const int bid = blockIdx.x;
  const int e = bid >> 6, rem = bid & 63, tt = rem >> 3, ht = rem & 7;
  const int t0 = e * TT + tt * 128, h0 = ht * 128;
  const float* Wd = Wdn + (size_t)e * II * HH;
  const int tid = threadIdx.x, w = tid >> 6, lane = tid & 63;
  const int wr = w >> 1, wc = w & 1, lrow = lane & 15, lk = (lane >> 4) * 8;
  f32x4 acc[4][4];
#pragma unroll
  for (int i = 0; i < 4; ++i)
#pragma unroll
    for (int j = 0; j < 4; ++j) acc[i][j] = (f32x4)(0.f);
  for (int k0 = 0; k0 < II; k0 += 32) {
#pragma unroll
    for (int l = 0; l < 2; ++l) {
      const int idx = tid + l * 256, row = idx >> 2, kq8 = idx & 3;
      *(uint4*)&As[row][kq8 * 8] = *(const uint4*)(hid + (size_t)(t0 + row) * II + k0 + kq8 * 8);
    }
#pragma unroll
    for (int l = 0; l < 2; ++l) {
      const int idx = tid + l * 256, col = idx & 127, kq8 = idx >> 7;
      union { unsigned short u[8]; uint4 v; } pk;
#pragma unroll
      for (int kk = 0; kk < 8; ++kk) pk.u[kk] = f2bf(Wd[(size_t)(k0 + kq8 * 8 + kk) * HH + h0 + col]);
      *(uint4*)&Bs[col][kq8 * 8] = pk.v;
    }
    __syncthreads();
    bf16x8 af[4], bfr[4];
#pragma unroll
    for (int mi = 0; mi < 4; ++mi) af[mi] = *(const bf16x8*)&As[wr * 64 + mi * 16 + lrow][lk];
#pragma unroll
    for (int nj = 0; nj < 4; ++nj) bfr[nj] = *(const bf16x8*)&Bs[wc * 64 + nj * 16 + lrow][lk];
#pragma unroll
    for (int mi = 0; mi < 4; ++mi)
#pragma unroll
      for (int nj = 0; nj < 4; ++nj)
        acc[mi][nj] = __builtin_amdgcn_mfma_f32_16x16x32_bf16(af[mi], bfr[nj], acc[mi][nj], 0, 0, 0);
    __syncthreads();
  }
  const float4* ha4 = (const float4*)ha;
  const float4* B4 = (const float4*)Bdn;
#pragma unroll
  for (int nj = 0; nj < 4; ++nj) {
    const int coln = h0 + wc * 64 + nj * 16 + lrow;
    const float4 b0 = B4[coln * 2], b1 = B4[coln * 2 + 1];
#pragma unroll
    for (int mi = 0; mi < 4; ++mi) {
      const int tb = t0 + wr * 64 + mi * 16 + (lane >> 4) * 4;
#pragma unroll
      for (int j = 0; j < 4; ++j) {
        const int t = tb + j;
        const float4 hr0 = ha4[t * 2], hr1 = ha4[t * 2 + 1];
        out[(size_t)t * HH + coln] = acc[mi][nj][j] + SCAL * (dot4(hr0, b0) + dot4(hr1, b1));
      }
    }
  }
}

extern "C" void kernel_launch(void* const* d_in, const int* in_sizes, int n_in,
                              void* d_out, int out_size, void* d_ws, size_t ws_size,
                              hipStream_t stream) {
  const float* x   = (const float*)d_in[0];
  const float* Wgu = (const float*)d_in[1];
  const float* Wdn = (const float*)d_in[2];
  const float* Agu = (const float*)d_in[3];
  const float* Bgu = (const float*)d_in[4];
  const float* Adn = (const float*)d_in[5];
  const float* Bdn = (const float*)d_in[6];
  float* out = (float*)d_out;

  char* ws = (char*)d_ws;
  unsigned short* hidden = (unsigned short*)ws;                      //  32 MB
  const size_t OFF_XB  = (size_t)NROW * II * 2;                      //  32 MB
  const size_t OFF_WGU = OFF_XB + (size_t)NROW * HH * 2;             //  48 MB
  const size_t OFF_WDN = OFF_WGU + (size_t)NE * FF2 * HH * 2;        // 112 MB
  const size_t OFF_XA  = OFF_WDN + (size_t)NE * HH * II * 2;         // 144 MB
  const size_t OFF_HA  = OFF_XA + (size_t)NROW * RR * 4;
  const size_t NEED    = OFF_HA + (size_t)NROW * RR * 4;

  if (ws_size >= NEED) {
    unsigned short* xb   = (unsigned short*)(ws + OFF_XB);
    unsigned short* WguT = (unsigned short*)(ws + OFF_WGU);
    unsigned short* WdnT = (unsigned short*)(ws + OFF_WDN);
    float* xa = (float*)(ws + OFF_XA);
    float* ha = (float*)(ws + OFF_HA);

    convx_kernel<<<(NROW * HH) / (256 * 8), 256, 0, stream>>>(x, xb);
    transconv_gu_kernel<<<NE * 16 * 64, 256, 0, stream>>>(Wgu, WguT);
    transconv_dn_kernel<<<NE * 32 * 16, 256, 0, stream>>>(Wdn, WdnT);
    rowdot_kernel<HH><<<NROW / 4, 256, 0, stream>>>(x, Agu, xa);
    gemm1_8p_kernel<<<NE * 8 * 32, 256, 0, stream>>>(xb, WguT, xa, Bgu, hidden);
    rowdot_bf16_kernel<<<NROW / 4, 256, 0, stream>>>(hidden, Adn, ha);
    gemm2_8p_kernel<<<NE * 8 * 8, 256, 0, stream>>>(hidden, WdnT, ha, Bdn, out);
  } else {
    float* xa = (float*)(ws + OFF_XB);
    float* ha = xa + (size_t)NROW * RR;
    rowdot_kernel<HH><<<NROW / 4, 256, 0, stream>>>(x, Agu, xa);
    gemm1_conv_kernel<<<NE * 8 * 32, 256, 0, stream>>>(x, Wgu, xa, Bgu, hidden);
    rowdot_bf16_kernel<<<NROW / 4, 256, 0, stream>>>(hidden, Adn, ha);
    gemm2_conv_kernel<<<NE * 8 * 8, 256, 0, stream>>>(hidden, Wdn, ha, Bdn, out);
  }
}

// Round 20
// 357.581 us; speedup vs baseline: 1.4711x; 1.2173x over previous
//
#include <hip/hip_runtime.h>
#include <math.h>

// Llama4 experts + shared LoRA (rank 8) — bf16 MFMA GEMMs.
// E=8, T=1024, H=1024, I=2048, F2=4096, R=8, scaling=2.
//
// R20 = revert to R16 champion (357.7us measured): dbuf 64KB LDS, merged
// single compute phase per K-tile (2 barriers + 1 lgkmcnt + counted vmcnt(8),
// 32 MFMA in one cluster), 128x128 tile, BK=64, 256 thr/4 waves, XOR
// slot-swizzle both-sides, XCD-colocate block swizzle, f2bf pre-passes.
// R17-R19 falsified the single-buffer/occupancy path: VGPR pinned at 172-176
// (2 waves/SIMD) for every 128^2 variant; launch_bounds arg2 unpredictable
// ((512,*)->128, (256,3)->84 w/ spill); single-buffer at same occupancy is
// strictly worse (225 vs 170us gemm1). Dbuf prefetch depth is the winner.

#define NE 8
#define TT 1024
#define HH 1024
#define II 2048
#define FF2 4096
#define RR 8
#define NROW (NE * TT)
#define SCAL 2.0f

typedef __bf16 bf16x8 __attribute__((ext_vector_type(8)));
typedef float f32x4 __attribute__((ext_vector_type(4)));

#define GLOAD16(g, l)                                                        \
  __builtin_amdgcn_global_load_lds((const __attribute__((address_space(1))) void*)(g), \
                                   (__attribute__((address_space(3))) void*)(l), 16, 0, 0)
#define BARRIER __builtin_amdgcn_s_barrier()
#define SB0 __builtin_amdgcn_sched_barrier(0)
#define WAITV8 asm volatile("s_waitcnt vmcnt(8)" ::: "memory")
#define WAITV0 asm volatile("s_waitcnt vmcnt(0)" ::: "memory")
#define WAITL0 asm volatile("s_waitcnt lgkmcnt(0)" ::: "memory")

__device__ __forceinline__ unsigned short f2bf(float f) {
  unsigned int u = __float_as_uint(f);
  u += 0x7fffu + ((u >> 16) & 1u);  // RNE
  return (unsigned short)(u >> 16);
}
__device__ __forceinline__ float dot4(float4 a, float4 b) {
  return a.x * b.x + a.y * b.y + a.z * b.z + a.w * b.w;
}

// ---------------- conversion pre-passes -------------------------------------
__global__ __launch_bounds__(256) void convx_kernel(const float* __restrict__ x,
                                                    unsigned short* __restrict__ xb) {
  const int i = blockIdx.x * 256 + threadIdx.x;
  const float4 a = *(const float4*)(x + (size_t)i * 8);
  const float4 b = *(const float4*)(x + (size_t)i * 8 + 4);
  union { unsigned short u[8]; uint4 v; } pk;
  pk.u[0] = f2bf(a.x); pk.u[1] = f2bf(a.y); pk.u[2] = f2bf(a.z); pk.u[3] = f2bf(a.w);
  pk.u[4] = f2bf(b.x); pk.u[5] = f2bf(b.y); pk.u[6] = f2bf(b.z); pk.u[7] = f2bf(b.w);
  *(uint4*)(xb + (size_t)i * 8) = pk.v;
}

// Wgu [e][1024][4096] f32 -> WguT [e][4096][1024] bf16, 16-granular interleave:
// gate col gc -> row (gc>>4)*32 + (gc&15); up col uc -> row (uc>>4)*32+16+(uc&15).
__global__ __launch_bounds__(256) void transconv_gu_kernel(const float* __restrict__ W,
                                                           unsigned short* __restrict__ WT) {
  __shared__ float ts[64][65];
  const int bid = blockIdx.x;           // 8*16*64
  const int nt = bid & 63, kt = (bid >> 6) & 15, e = bid >> 10;
  const float* Win = W + (size_t)e * HH * FF2 + (size_t)(kt * 64) * FF2 + nt * 64;
  const int tid = threadIdx.x;
#pragma unroll
  for (int l = 0; l < 4; ++l) {
    const int idx = tid + l * 256, r = idx >> 4, c4 = idx & 15;
    const float4 v = *(const float4*)(Win + (size_t)r * FF2 + c4 * 4);
    ts[r][c4 * 4 + 0] = v.x; ts[r][c4 * 4 + 1] = v.y;
    ts[r][c4 * 4 + 2] = v.z; ts[r][c4 * 4 + 3] = v.w;
  }
  __syncthreads();
  unsigned short* We = WT + (size_t)e * FF2 * HH;
#pragma unroll
  for (int l = 0; l < 2; ++l) {
    const int idx = tid + l * 256, j = idx >> 3, q = idx & 7;
    int orow;
    if (nt < 32) orow = (nt * 4 + (j >> 4)) * 32 + (j & 15);             // gate
    else         orow = ((nt - 32) * 4 + (j >> 4)) * 32 + 16 + (j & 15); // up
    union { unsigned short u[8]; uint4 v; } pk;
#pragma unroll
    for (int kk = 0; kk < 8; ++kk) pk.u[kk] = f2bf(ts[q * 8 + kk][j]);
    *(uint4*)(We + (size_t)orow * HH + kt * 64 + q * 8) = pk.v;
  }
}

// Wdn [e][2048][1024] f32 -> WdnT [e][1024][2048] bf16 (plain transpose).
__global__ __launch_bounds__(256) void transconv_dn_kernel(const float* __restrict__ W,
                                                           unsigned short* __restrict__ WT) {
  __shared__ float ts[64][65];
  const int bid = blockIdx.x;           // 8*32*16
  const int nt = bid & 15, kt = (bid >> 4) & 31, e = bid >> 9;
  const float* Win = W + (size_t)e * II * HH + (size_t)(kt * 64) * HH + nt * 64;
  const int tid = threadIdx.x;
#pragma unroll
  for (int l = 0; l < 4; ++l) {
    const int idx = tid + l * 256, r = idx >> 4, c4 = idx & 15;
    const float4 v = *(const float4*)(Win + (size_t)r * HH + c4 * 4);
    ts[r][c4 * 4 + 0] = v.x; ts[r][c4 * 4 + 1] = v.y;
    ts[r][c4 * 4 + 2] = v.z; ts[r][c4 * 4 + 3] = v.w;
  }
  __syncthreads();
  unsigned short* Wout = WT + (size_t)e * HH * II + (size_t)(nt * 64) * II + kt * 64;
#pragma unroll
  for (int l = 0; l < 2; ++l) {
    const int idx = tid + l * 256, j = idx >> 3, q = idx & 7;
    union { unsigned short u[8]; uint4 v; } pk;
#pragma unroll
    for (int kk = 0; kk < 8; ++kk) pk.u[kk] = f2bf(ts[q * 8 + kk][j]);
    *(uint4*)(Wout + (size_t)j * II + q * 8) = pk.v;
  }
}

// ---------------- rank-8 row dots -------------------------------------------
template <int K>
__global__ __launch_bounds__(256) void rowdot_kernel(const float* __restrict__ x,
                                                     const float* __restrict__ A,
                                                     float* __restrict__ xa) {
  const int w = threadIdx.x >> 6, lane = threadIdx.x & 63;
  const int t = blockIdx.x * 4 + w;
  const float* xrow = x + (size_t)t * K;
  float acc[RR];
#pragma unroll
  for (int r = 0; r < RR; ++r) acc[r] = 0.f;
#pragma unroll
  for (int c = 0; c < K / 256; ++c) {
    const float4 xv = *(const float4*)(xrow + c * 256 + lane * 4);
#pragma unroll
    for (int r = 0; r < RR; ++r) {
      const float4 av = *(const float4*)(A + (size_t)r * K + c * 256 + lane * 4);
      acc[r] += dot4(xv, av);
    }
  }
#pragma unroll
  for (int r = 0; r < RR; ++r) {
    float v = acc[r];
#pragma unroll
    for (int off = 32; off > 0; off >>= 1) v += __shfl_down(v, off, 64);
    if (lane == 0) xa[(size_t)t * RR + r] = v;
  }
}

__global__ __launch_bounds__(256) void rowdot_bf16_kernel(const unsigned short* __restrict__ h,
                                                          const float* __restrict__ A,
                                                          float* __restrict__ ha) {
  const int w = threadIdx.x >> 6, lane = threadIdx.x & 63;
  const int t = blockIdx.x * 4 + w;
  const unsigned short* hrow = h + (size_t)t * II;
  float acc[RR];
#pragma unroll
  for (int r = 0; r < RR; ++r) acc[r] = 0.f;
#pragma unroll
  for (int c = 0; c < II / 512; ++c) {
    const uint4 v = *(const uint4*)(hrow + c * 512 + lane * 8);
    float xv[8];
    xv[0] = __uint_as_float(v.x << 16); xv[1] = __uint_as_float(v.x & 0xffff0000u);
    xv[2] = __uint_as_float(v.y << 16); xv[3] = __uint_as_float(v.y & 0xffff0000u);
    xv[4] = __uint_as_float(v.z << 16); xv[5] = __uint_as_float(v.z & 0xffff0000u);
    xv[6] = __uint_as_float(v.w << 16); xv[7] = __uint_as_float(v.w & 0xffff0000u);
#pragma unroll
    for (int r = 0; r < RR; ++r) {
      const float4 a0 = *(const float4*)(A + (size_t)r * II + c * 512 + lane * 8);
      const float4 a1 = *(const float4*)(A + (size_t)r * II + c * 512 + lane * 8 + 4);
      acc[r] += xv[0] * a0.x + xv[1] * a0.y + xv[2] * a0.z + xv[3] * a0.w +
                xv[4] * a1.x + xv[5] * a1.y + xv[6] * a1.z + xv[7] * a1.w;
    }
  }
#pragma unroll
  for (int r = 0; r < RR; ++r) {
    float v = acc[r];
#pragma unroll
    for (int off = 32; off > 0; off >>= 1) v += __shfl_down(v, off, 64);
    if (lane == 0) ha[(size_t)t * RR + r] = v;
  }
}

// ---------------- gemm1: 128x128, BK=64, 4 waves, 1 compute phase/tile ------
// B panel = 128 WguT rows = 64 hidden cols (16-granular gate/up interleave).
// Wave wc owns B rows [wc*64, wc*64+64): n-frag parity = gate/up; pairs
// (2f,2f+1) share hidden-col block it*4 + wc*2 + f. acc[4][4]=64 f32/thread.
__global__ __launch_bounds__(256) void gemm1_8p_kernel(
    const unsigned short* __restrict__ xb, const unsigned short* __restrict__ WguT,
    const float* __restrict__ xa, const float* __restrict__ Bgu,
    unsigned short* __restrict__ hidden) {
  __shared__ unsigned short sm[2][16384];  // A 128x64 @0, B 128x64 @byte16384; 64KB

  const int bid = blockIdx.x;          // 2048 = 8e * 8tt * 32it (swizzled)
  const int e = bid & 7;
  const int s = bid >> 3;              // 0..255
  const int g = s >> 6, wq = s & 63;   // groups of {8tt x 8it} = 4MB L2 set
  const int tt = wq >> 3, it = (g << 3) | (wq & 7);
  const int t0 = e * TT + tt * 128;
  const unsigned short* Ag = xb + (size_t)t0 * HH;
  const unsigned short* Bg = WguT + (size_t)e * FF2 * HH + (size_t)(it * 128) * HH;

  const int tid = threadIdx.x;
  const int w = tid >> 6, lane = tid & 63;
  const int wr = w >> 1, wc = w & 1;
  const int lrow = lane & 15, lkg = lane >> 4;

  auto stageA = [&](int buf, int kt, int h) {
#pragma unroll
    for (int l = 0; l < 2; ++l) {
      const int i = tid + l * 256;
      const int r = i >> 3, sl = i & 7;
      const int row = h * 64 + r;
      GLOAD16((const char*)(Ag + (size_t)row * HH + kt * 64 + ((sl ^ (row & 7)) << 3)),
              (char*)&sm[buf][0] + row * 128 + sl * 16);
    }
  };
  auto stageB = [&](int buf, int kt, int h) {
#pragma unroll
    for (int l = 0; l < 2; ++l) {
      const int i = tid + l * 256;
      const int r = i >> 3, sl = i & 7;
      const int row = h * 64 + r;
      GLOAD16((const char*)(Bg + (size_t)row * HH + kt * 64 + ((sl ^ (row & 7)) << 3)),
              (char*)&sm[buf][0] + 16384 + row * 128 + sl * 16);
    }
  };
  auto ldA = [&](int p, int mIdx, int s2) -> bf16x8 {
    const int row = wr * 64 + mIdx * 16 + lrow;
    const int sl = (s2 * 4 + lkg) ^ (row & 7);
    return *(const bf16x8*)((const char*)&sm[p][0] + row * 128 + sl * 16);
  };
  auto ldB = [&](int p, int nj, int s2) -> bf16x8 {
    const int row = wc * 64 + nj * 16 + lrow;
    const int sl = (s2 * 4 + lkg) ^ (row & 7);
    return *(const bf16x8*)((const char*)&sm[p][0] + 16384 + row * 128 + sl * 16);
  };

  f32x4 acc[4][4];
#pragma unroll
  for (int i = 0; i < 4; ++i)
#pragma unroll
    for (int j = 0; j < 4; ++j) acc[i][j] = (f32x4)(0.f);

  stageA(0, 0, 0); stageA(0, 0, 1); stageB(0, 0, 0); stageB(0, 0, 1);

  const int NT = HH / 64;  // 16
  for (int t = 0; t < NT; ++t) {
    const int p = t & 1, q = p ^ 1;
    if (t + 1 < NT) {
      stageA(q, t + 1, 0); stageA(q, t + 1, 1);
      stageB(q, t + 1, 0); stageB(q, t + 1, 1);
      WAITV8;
    } else {
      WAITV0;
    }
    SB0; BARRIER;
    bf16x8 af[4][2], bfr[4][2];
#pragma unroll
    for (int mi = 0; mi < 4; ++mi) { af[mi][0] = ldA(p, mi, 0); af[mi][1] = ldA(p, mi, 1); }
#pragma unroll
    for (int nj = 0; nj < 4; ++nj) { bfr[nj][0] = ldB(p, nj, 0); bfr[nj][1] = ldB(p, nj, 1); }
    WAITL0; SB0;
    __builtin_amdgcn_s_setprio(1);
#pragma unroll
    for (int mi = 0; mi < 4; ++mi)
#pragma unroll
      for (int nj = 0; nj < 4; ++nj)
#pragma unroll
        for (int s2 = 0; s2 < 2; ++s2)
          acc[mi][nj] = __builtin_amdgcn_mfma_f32_16x16x32_bf16(af[mi][s2], bfr[nj][s2], acc[mi][nj], 0, 0, 0);
    __builtin_amdgcn_s_setprio(0); SB0; BARRIER;
  }

  // epilogue: LoRA + SwiGLU, bf16 store. n-frag pairs (2f, 2f+1) = (gate, up)
  // for hidden col block it*4 + wc*2 + f.
  const float4* xa4 = (const float4*)xa;
  const float4* B4 = (const float4*)Bgu;
#pragma unroll
  for (int f = 0; f < 2; ++f) {
    const int gc = it * 64 + (wc * 2 + f) * 16 + lrow;
    const float4 bg0 = B4[gc * 2], bg1 = B4[gc * 2 + 1];
    const float4 bu0 = B4[(II + gc) * 2], bu1 = B4[(II + gc) * 2 + 1];
#pragma unroll
    for (int m = 0; m < 4; ++m) {
      const int tb = t0 + wr * 64 + m * 16 + lkg * 4;
#pragma unroll
      for (int j = 0; j < 4; ++j) {
        const int trow = tb + j;
        const float4 xr0 = xa4[trow * 2], xr1 = xa4[trow * 2 + 1];
        const float gv = acc[m][f * 2 + 0][j] + SCAL * (dot4(xr0, bg0) + dot4(xr1, bg1));
        const float uv = acc[m][f * 2 + 1][j] + SCAL * (dot4(xr0, bu0) + dot4(xr1, bu1));
        const float sg = gv / (1.f + __expf(-gv));
        hidden[(size_t)trow * II + gc] = f2bf(uv * sg);
      }
    }
  }
}

// ---------------- gemm2: 128x128, BK=64, 4 waves, 1 compute phase/tile ------
__global__ __launch_bounds__(256) void gemm2_8p_kernel(
    const unsigned short* __restrict__ hid, const unsigned short* __restrict__ WdnT,
    const float* __restrict__ ha, const float* __restrict__ Bdn,
    float* __restrict__ out) {
  __shared__ unsigned short sm[2][16384];  // A 128x64 @0, B 128x64 @byte16384; 64KB

  const int bid = blockIdx.x;          // 512 = 8e * 8tt * 8ht (swizzled)
  const int e = bid & 7;
  const int s = bid >> 3;              // 0..63
  const int g = s >> 4, wq = s & 15;   // groups of {4tt x 4ht} = 4MB L2 set
  const int tt = (g >> 1) * 4 + (wq >> 2);
  const int ht = (g & 1) * 4 + (wq & 3);
  const int t0 = e * TT + tt * 128;
  const int h0 = ht * 128;
  const unsigned short* Ag = hid + (size_t)t0 * II;
  const unsigned short* Bg = WdnT + (size_t)e * HH * II + (size_t)h0 * II;

  const int tid = threadIdx.x;
  const int w = tid >> 6, lane = tid & 63;
  const int wr = w >> 1, wc = w & 1;
  const int lrow = lane & 15, lkg = lane >> 4;

  auto stageA = [&](int buf, int kt, int h) {
#pragma unroll
    for (int l = 0; l < 2; ++l) {
      const int i = tid + l * 256;
      const int r = i >> 3, sl = i & 7;
      const int row = h * 64 + r;
      GLOAD16((const char*)(Ag + (size_t)row * II + kt * 64 + ((sl ^ (row & 7)) << 3)),
              (char*)&sm[buf][0] + row * 128 + sl * 16);
    }
  };
  auto stageB = [&](int buf, int kt, int h) {
#pragma unroll
    for (int l = 0; l < 2; ++l) {
      const int i = tid + l * 256;
      const int r = i >> 3, sl = i & 7;
      const int row = h * 64 + r;
      GLOAD16((const char*)(Bg + (size_t)row * II + kt * 64 + ((sl ^ (row & 7)) << 3)),
              (char*)&sm[buf][0] + 16384 + row * 128 + sl * 16);
    }
  };
  auto ldA = [&](int p, int mIdx, int s2) -> bf16x8 {
    const int row = wr * 64 + mIdx * 16 + lrow;
    const int sl = (s2 * 4 + lkg) ^ (row & 7);
    return *(const bf16x8*)((const char*)&sm[p][0] + row * 128 + sl * 16);
  };
  auto ldB = [&](int p, int nj, int s2) -> bf16x8 {
    const int row = wc * 64 + nj * 16 + lrow;
    const int sl = (s2 * 4 + lkg) ^ (row & 7);
    return *(const bf16x8*)((const char*)&sm[p][0] + 16384 + row * 128 + sl * 16);
  };

  f32x4 acc[4][4];
#pragma unroll
  for (int i = 0; i < 4; ++i)
#pragma unroll
    for (int j = 0; j < 4; ++j) acc[i][j] = (f32x4)(0.f);

  stageA(0, 0, 0); stageA(0, 0, 1); stageB(0, 0, 0); stageB(0, 0, 1);

  const int NT = II / 64;  // 32
  for (int t = 0; t < NT; ++t) {
    const int p = t & 1, q = p ^ 1;
    if (t + 1 < NT) {
      stageA(q, t + 1, 0); stageA(q, t + 1, 1);
      stageB(q, t + 1, 0); stageB(q, t + 1, 1);
      WAITV8;
    } else {
      WAITV0;
    }
    SB0; BARRIER;
    bf16x8 af[4][2], bfr[4][2];
#pragma unroll
    for (int mi = 0; mi < 4; ++mi) { af[mi][0] = ldA(p, mi, 0); af[mi][1] = ldA(p, mi, 1); }
#pragma unroll
    for (int nj = 0; nj < 4; ++nj) { bfr[nj][0] = ldB(p, nj, 0); bfr[nj][1] = ldB(p, nj, 1); }
    WAITL0; SB0;
    __builtin_amdgcn_s_setprio(1);
#pragma unroll
    for (int mi = 0; mi < 4; ++mi)
#pragma unroll
      for (int nj = 0; nj < 4; ++nj)
#pragma unroll
        for (int s2 = 0; s2 < 2; ++s2)
          acc[mi][nj] = __builtin_amdgcn_mfma_f32_16x16x32_bf16(af[mi][s2], bfr[nj][s2], acc[mi][nj], 0, 0, 0);
    __builtin_amdgcn_s_setprio(0); SB0; BARRIER;
  }

  const float4* ha4 = (const float4*)ha;
  const float4* B4 = (const float4*)Bdn;
#pragma unroll
  for (int nj = 0; nj < 4; ++nj) {
    const int col = h0 + wc * 64 + nj * 16 + lrow;
    const float4 b0 = B4[col * 2], b1 = B4[col * 2 + 1];
#pragma unroll
    for (int m = 0; m < 4; ++m) {
      const int tb = t0 + wr * 64 + m * 16 + lkg * 4;
#pragma unroll
      for (int j = 0; j < 4; ++j) {
        const int trow = tb + j;
        const float4 hr0 = ha4[trow * 2], hr1 = ha4[trow * 2 + 1];
        out[(size_t)trow * HH + col] = acc[m][nj][j] + SCAL * (dot4(hr0, b0) + dot4(hr1, b1));
      }
    }
  }
}

// ---------------- fallback (R3): in-loop conversion GEMMs -------------------
__global__ __launch_bounds__(256) void gemm1_conv_kernel(const float* __restrict__ x,
                                                         const float* __restrict__ Wgu,
                                                         const float* __restrict__ xa,
                                                         const float* __restrict__ Bgu,
                                                         unsigned short* __restrict__ hidden) {
  __shared__ unsigned short As[128][40];
  __shared__ unsigned short Bs[128][40];
  const int bid = blockIdx.x;
  const int e = bid >> 8, rem = bid & 255, tt = rem >> 5, it = rem & 31;
  const int t0 = e * TT + tt * 128, i0 = it * 64;
  const float* Wg = Wgu + (size_t)e * HH * FF2;
  const int tid = threadIdx.x, w = tid >> 6, lane = tid & 63;
  const int wr = w >> 1, wc = w & 1, lrow = lane & 15, lk = (lane >> 4) * 8;
  f32x4 acc[4][4];
#pragma unroll
  for (int i = 0; i < 4; ++i)
#pragma unroll
    for (int j = 0; j < 4; ++j) acc[i][j] = (f32x4)(0.f);
  for (int k0 = 0; k0 < HH; k0 += 32) {
#pragma unroll
    for (int l = 0; l < 4; ++l) {
      const int idx = tid + l * 256, row = idx >> 3, kq = idx & 7;
      const float4 v = *(const float4*)(x + (size_t)(t0 + row) * HH + k0 + kq * 4);
      ushort4 p; p.x = f2bf(v.x); p.y = f2bf(v.y); p.z = f2bf(v.z); p.w = f2bf(v.w);
      *(ushort4*)&As[row][kq * 4] = p;
    }
#pragma unroll
    for (int l = 0; l < 2; ++l) {
      const int idx = tid + l * 256, col = idx & 127, kq8 = idx >> 7;
      const int gcol = i0 + (col & 63) + ((col >> 6) * II);
      union { unsigned short u[8]; uint4 v; } pk;
#pragma unroll
      for (int kk = 0; kk < 8; ++kk) pk.u[kk] = f2bf(Wg[(size_t)(k0 + kq8 * 8 + kk) * FF2 + gcol]);
      *(uint4*)&Bs[col][kq8 * 8] = pk.v;
    }
    __syncthreads();
    bf16x8 af[4], bfr[4];
#pragma unroll
    for (int mi = 0; mi < 4; ++mi) af[mi] = *(const bf16x8*)&As[wr * 64 + mi * 16 + lrow][lk];
#pragma unroll
    for (int nj = 0; nj < 4; ++nj) {
      const int c = (nj < 2) ? (wc * 32 + nj * 16) : (64 + wc * 32 + (nj - 2) * 16);
      bfr[nj] = *(const bf16x8*)&Bs[c + lrow][lk];
    }
#pragma unroll
    for (int mi = 0; mi < 4; ++mi)
#pragma unroll
      for (int nj = 0; nj < 4; ++nj)
        acc[mi][nj] = __builtin_amdgcn_mfma_f32_16x16x32_bf16(af[mi], bfr[nj], acc[mi][nj], 0, 0, 0);
    __syncthreads();
  }
  const float4* xa4 = (const float4*)xa;
  const float4* B4 = (const float4*)Bgu;
#pragma unroll
  for (int nj = 0; nj < 2; ++nj) {
    const int coln = i0 + wc * 32 + nj * 16 + lrow;
    const float4 bg0 = B4[coln * 2], bg1 = B4[coln * 2 + 1];
    const float4 bu0 = B4[(II + coln) * 2], bu1 = B4[(II + coln) * 2 + 1];
#pragma unroll
    for (int mi = 0; mi < 4; ++mi) {
      const int tb = t0 + wr * 64 + mi * 16 + (lane >> 4) * 4;
#pragma unroll
      for (int j = 0; j < 4; ++j) {
        const int t = tb + j;
        const float4 xr0 = xa4[t * 2], xr1 = xa4[t * 2 + 1];
        const float g = acc[mi][nj][j] + SCAL * (dot4(xr0, bg0) + dot4(xr1, bg1));
        const float u = acc[mi][nj + 2][j] + SCAL * (dot4(xr0, bu0) + dot4(xr1, bu1));
        const float s = g / (1.f + __expf(-g));
        hidden[(size_t)t * II + coln] = f2bf(u * s);
      }
    }
  }
}

__global__ __launch_bounds__(256) void gemm2_conv_kernel(const unsigned short* __restrict__ hid,
                                                         const float* __restrict__ Wdn,
                                                         const float* __restrict__ ha,
                                                         const float* __restrict__ Bdn,
                                                         float* __restrict__ out) {
  __shared__ unsigned short As[128][40];
  __shared__ unsigned short Bs[128][40];
  const int bid = blockIdx.x;
  const int e = bid >> 6, rem = bid & 63, tt = rem >> 3, ht = rem & 7;
  const int t0 = e * TT + tt * 128, h0 = ht * 128;
  const float* Wd = Wdn + (size_t)e * II * HH;
  const int tid = threadIdx.x, w = tid >> 6, lane = tid & 63;
  const int wr = w >> 1, wc = w & 1, lrow = lane & 15, lk = (lane >> 4) * 8;
  f32x4 acc[4][4];
#pragma unroll
  for (int i = 0; i < 4; ++i)
#pragma unroll
    for (int j = 0; j < 4; ++j) acc[i][j] = (f32x4)(0.f);
  for (int k0 = 0; k0 < II; k0 += 32) {
#pragma unroll
    for (int l = 0; l < 2; ++l) {
      const int idx = tid + l * 256, row = idx >> 2, kq8 = idx & 3;
      *(uint4*)&As[row][kq8 * 8] = *(const uint4*)(hid + (size_t)(t0 + row) * II + k0 + kq8 * 8);
    }
#pragma unroll
    for (int l = 0; l < 2; ++l) {
      const int idx = tid + l * 256, col = idx & 127, kq8 = idx >> 7;
      union { unsigned short u[8]; uint4 v; } pk;
#pragma unroll
      for (int kk = 0; kk < 8; ++kk) pk.u[kk] = f2bf(Wd[(size_t)(k0 + kq8 * 8 + kk) * HH + h0 + col]);
      *(uint4*)&Bs[col][kq8 * 8] = pk.v;
    }
    __syncthreads();
    bf16x8 af[4], bfr[4];
#pragma unroll
    for (int mi = 0; mi < 4; ++mi) af[mi] = *(const bf16x8*)&As[wr * 64 + mi * 16 + lrow][lk];
#pragma unroll
    for (int nj = 0; nj < 4; ++nj) bfr[nj] = *(const bf16x8*)&Bs[wc * 64 + nj * 16 + lrow][lk];
#pragma unroll
    for (int mi = 0; mi < 4; ++mi)
#pragma unroll
      for (int nj = 0; nj < 4; ++nj)
        acc[mi][nj] = __builtin_amdgcn_mfma_f32_16x16x32_bf16(af[mi], bfr[nj], acc[mi][nj], 0, 0, 0);
    __syncthreads();
  }
  const float4* ha4 = (const float4*)ha;
  const float4* B4 = (const float4*)Bdn;
#pragma unroll
  for (int nj = 0; nj < 4; ++nj) {
    const int coln = h0 + wc * 64 + nj * 16 + lrow;
    const float4 b0 = B4[coln * 2], b1 = B4[coln * 2 + 1];
#pragma unroll
    for (int mi = 0; mi < 4; ++mi) {
      const int tb = t0 + wr * 64 + mi * 16 + (lane >> 4) * 4;
#pragma unroll
      for (int j = 0; j < 4; ++j) {
        const int t = tb + j;
        const float4 hr0 = ha4[t * 2], hr1 = ha4[t * 2 + 1];
        out[(size_t)t * HH + coln] = acc[mi][nj][j] + SCAL * (dot4(hr0, b0) + dot4(hr1, b1));
      }
    }
  }
}

extern "C" void kernel_launch(void* const* d_in, const int* in_sizes, int n_in,
                              void* d_out, int out_size, void* d_ws, size_t ws_size,
                              hipStream_t stream) {
  const float* x   = (const float*)d_in[0];
  const float* Wgu = (const float*)d_in[1];
  const float* Wdn = (const float*)d_in[2];
  const float* Agu = (const float*)d_in[3];
  const float* Bgu = (const float*)d_in[4];
  const float* Adn = (const float*)d_in[5];
  const float* Bdn = (const float*)d_in[6];
  float* out = (float*)d_out;

  char* ws = (char*)d_ws;
  unsigned short* hidden = (unsigned short*)ws;                      //  32 MB
  const size_t OFF_XB  = (size_t)NROW * II * 2;                      //  32 MB
  const size_t OFF_WGU = OFF_XB + (size_t)NROW * HH * 2;             //  48 MB
  const size_t OFF_WDN = OFF_WGU + (size_t)NE * FF2 * HH * 2;        // 112 MB
  const size_t OFF_XA  = OFF_WDN + (size_t)NE * HH * II * 2;         // 144 MB
  const size_t OFF_HA  = OFF_XA + (size_t)NROW * RR * 4;
  const size_t NEED    = OFF_HA + (size_t)NROW * RR * 4;

  if (ws_size >= NEED) {
    unsigned short* xb   = (unsigned short*)(ws + OFF_XB);
    unsigned short* WguT = (unsigned short*)(ws + OFF_WGU);
    unsigned short* WdnT = (unsigned short*)(ws + OFF_WDN);
    float* xa = (float*)(ws + OFF_XA);
    float* ha = (float*)(ws + OFF_HA);

    convx_kernel<<<(NROW * HH) / (256 * 8), 256, 0, stream>>>(x, xb);
    transconv_gu_kernel<<<NE * 16 * 64, 256, 0, stream>>>(Wgu, WguT);
    transconv_dn_kernel<<<NE * 32 * 16, 256, 0, stream>>>(Wdn, WdnT);
    rowdot_kernel<HH><<<NROW / 4, 256, 0, stream>>>(x, Agu, xa);
    gemm1_8p_kernel<<<NE * 8 * 32, 256, 0, stream>>>(xb, WguT, xa, Bgu, hidden);
    rowdot_bf16_kernel<<<NROW / 4, 256, 0, stream>>>(hidden, Adn, ha);
    gemm2_8p_kernel<<<NE * 8 * 8, 256, 0, stream>>>(hidden, WdnT, ha, Bdn, out);
  } else {
    float* xa = (float*)(ws + OFF_XB);
    float* ha = xa + (size_t)NROW * RR;
    rowdot_kernel<HH><<<NROW / 4, 256, 0, stream>>>(x, Agu, xa);
    gemm1_conv_kernel<<<NE * 8 * 32, 256, 0, stream>>>(x, Wgu, xa, Bgu, hidden);
    rowdot_bf16_kernel<<<NROW / 4, 256, 0, stream>>>(hidden, Adn, ha);
    gemm2_conv_kernel<<<NE * 8 * 8, 256, 0, stream>>>(hidden, Wdn, ha, Bdn, out);
  }
}

// Round 21
// 352.683 us; speedup vs baseline: 1.4915x; 1.0139x over previous
//
#include <hip/hip_runtime.h>
#include <math.h>

// Llama4 experts + shared LoRA (rank 8) — bf16 MFMA GEMMs.
// E=8, T=1024, H=1024, I=2048, F2=4096, R=8, scaling=2.
//
// R20->R21: champion (357.6us, reproduced twice) minus three scheduling
// pins the guide measures as neutral/harmful in this lockstep regime:
//   - WAITL0 (lgkmcnt(0)) removed: compiler emits fine-grained lgkm waits,
//     interleaving ds_reads with MFMAs (m97 asm) instead of full drain.
//   - sched_barrier(0) removed (order-pinning regressed m141).
//   - setprio removed (null/negative on single-phase lockstep GEMM, m190).
// Kept: counted vmcnt(8) + raw s_barrier (compiler doesn't model
// global_load_lds->LDS deps) + a zero-cost compiler fence before the
// closing barrier so ds_reads can't be compiler-sunk past it.
// Structure otherwise identical: dbuf 64KB LDS, 1 compute phase/K-tile,
// 128x128 tile, BK=64, 256 thr/4 waves, XOR slot-swizzle both-sides,
// XCD-colocate block swizzle, f2bf pre-passes, LoRA/SwiGLU epilogues.

#define NE 8
#define TT 1024
#define HH 1024
#define II 2048
#define FF2 4096
#define RR 8
#define NROW (NE * TT)
#define SCAL 2.0f

typedef __bf16 bf16x8 __attribute__((ext_vector_type(8)));
typedef float f32x4 __attribute__((ext_vector_type(4)));

#define GLOAD16(g, l)                                                        \
  __builtin_amdgcn_global_load_lds((const __attribute__((address_space(1))) void*)(g), \
                                   (__attribute__((address_space(3))) void*)(l), 16, 0, 0)
#define BARRIER __builtin_amdgcn_s_barrier()
#define CFENCE asm volatile("" ::: "memory")
#define WAITV8 asm volatile("s_waitcnt vmcnt(8)" ::: "memory")
#define WAITV0 asm volatile("s_waitcnt vmcnt(0)" ::: "memory")

__device__ __forceinline__ unsigned short f2bf(float f) {
  unsigned int u = __float_as_uint(f);
  u += 0x7fffu + ((u >> 16) & 1u);  // RNE
  return (unsigned short)(u >> 16);
}
__device__ __forceinline__ float dot4(float4 a, float4 b) {
  return a.x * b.x + a.y * b.y + a.z * b.z + a.w * b.w;
}

// ---------------- conversion pre-passes -------------------------------------
__global__ __launch_bounds__(256) void convx_kernel(const float* __restrict__ x,
                                                    unsigned short* __restrict__ xb) {
  const int i = blockIdx.x * 256 + threadIdx.x;
  const float4 a = *(const float4*)(x + (size_t)i * 8);
  const float4 b = *(const float4*)(x + (size_t)i * 8 + 4);
  union { unsigned short u[8]; uint4 v; } pk;
  pk.u[0] = f2bf(a.x); pk.u[1] = f2bf(a.y); pk.u[2] = f2bf(a.z); pk.u[3] = f2bf(a.w);
  pk.u[4] = f2bf(b.x); pk.u[5] = f2bf(b.y); pk.u[6] = f2bf(b.z); pk.u[7] = f2bf(b.w);
  *(uint4*)(xb + (size_t)i * 8) = pk.v;
}

// Wgu [e][1024][4096] f32 -> WguT [e][4096][1024] bf16, 16-granular interleave:
// gate col gc -> row (gc>>4)*32 + (gc&15); up col uc -> row (uc>>4)*32+16+(uc&15).
__global__ __launch_bounds__(256) void transconv_gu_kernel(const float* __restrict__ W,
                                                           unsigned short* __restrict__ WT) {
  __shared__ float ts[64][65];
  const int bid = blockIdx.x;           // 8*16*64
  const int nt = bid & 63, kt = (bid >> 6) & 15, e = bid >> 10;
  const float* Win = W + (size_t)e * HH * FF2 + (size_t)(kt * 64) * FF2 + nt * 64;
  const int tid = threadIdx.x;
#pragma unroll
  for (int l = 0; l < 4; ++l) {
    const int idx = tid + l * 256, r = idx >> 4, c4 = idx & 15;
    const float4 v = *(const float4*)(Win + (size_t)r * FF2 + c4 * 4);
    ts[r][c4 * 4 + 0] = v.x; ts[r][c4 * 4 + 1] = v.y;
    ts[r][c4 * 4 + 2] = v.z; ts[r][c4 * 4 + 3] = v.w;
  }
  __syncthreads();
  unsigned short* We = WT + (size_t)e * FF2 * HH;
#pragma unroll
  for (int l = 0; l < 2; ++l) {
    const int idx = tid + l * 256, j = idx >> 3, q = idx & 7;
    int orow;
    if (nt < 32) orow = (nt * 4 + (j >> 4)) * 32 + (j & 15);             // gate
    else         orow = ((nt - 32) * 4 + (j >> 4)) * 32 + 16 + (j & 15); // up
    union { unsigned short u[8]; uint4 v; } pk;
#pragma unroll
    for (int kk = 0; kk < 8; ++kk) pk.u[kk] = f2bf(ts[q * 8 + kk][j]);
    *(uint4*)(We + (size_t)orow * HH + kt * 64 + q * 8) = pk.v;
  }
}

// Wdn [e][2048][1024] f32 -> WdnT [e][1024][2048] bf16 (plain transpose).
__global__ __launch_bounds__(256) void transconv_dn_kernel(const float* __restrict__ W,
                                                           unsigned short* __restrict__ WT) {
  __shared__ float ts[64][65];
  const int bid = blockIdx.x;           // 8*32*16
  const int nt = bid & 15, kt = (bid >> 4) & 31, e = bid >> 9;
  const float* Win = W + (size_t)e * II * HH + (size_t)(kt * 64) * HH + nt * 64;
  const int tid = threadIdx.x;
#pragma unroll
  for (int l = 0; l < 4; ++l) {
    const int idx = tid + l * 256, r = idx >> 4, c4 = idx & 15;
    const float4 v = *(const float4*)(Win + (size_t)r * HH + c4 * 4);
    ts[r][c4 * 4 + 0] = v.x; ts[r][c4 * 4 + 1] = v.y;
    ts[r][c4 * 4 + 2] = v.z; ts[r][c4 * 4 + 3] = v.w;
  }
  __syncthreads();
  unsigned short* Wout = WT + (size_t)e * HH * II + (size_t)(nt * 64) * II + kt * 64;
#pragma unroll
  for (int l = 0; l < 2; ++l) {
    const int idx = tid + l * 256, j = idx >> 3, q = idx & 7;
    union { unsigned short u[8]; uint4 v; } pk;
#pragma unroll
    for (int kk = 0; kk < 8; ++kk) pk.u[kk] = f2bf(ts[q * 8 + kk][j]);
    *(uint4*)(Wout + (size_t)j * II + q * 8) = pk.v;
  }
}

// ---------------- rank-8 row dots -------------------------------------------
template <int K>
__global__ __launch_bounds__(256) void rowdot_kernel(const float* __restrict__ x,
                                                     const float* __restrict__ A,
                                                     float* __restrict__ xa) {
  const int w = threadIdx.x >> 6, lane = threadIdx.x & 63;
  const int t = blockIdx.x * 4 + w;
  const float* xrow = x + (size_t)t * K;
  float acc[RR];
#pragma unroll
  for (int r = 0; r < RR; ++r) acc[r] = 0.f;
#pragma unroll
  for (int c = 0; c < K / 256; ++c) {
    const float4 xv = *(const float4*)(xrow + c * 256 + lane * 4);
#pragma unroll
    for (int r = 0; r < RR; ++r) {
      const float4 av = *(const float4*)(A + (size_t)r * K + c * 256 + lane * 4);
      acc[r] += dot4(xv, av);
    }
  }
#pragma unroll
  for (int r = 0; r < RR; ++r) {
    float v = acc[r];
#pragma unroll
    for (int off = 32; off > 0; off >>= 1) v += __shfl_down(v, off, 64);
    if (lane == 0) xa[(size_t)t * RR + r] = v;
  }
}

__global__ __launch_bounds__(256) void rowdot_bf16_kernel(const unsigned short* __restrict__ h,
                                                          const float* __restrict__ A,
                                                          float* __restrict__ ha) {
  const int w = threadIdx.x >> 6, lane = threadIdx.x & 63;
  const int t = blockIdx.x * 4 + w;
  const unsigned short* hrow = h + (size_t)t * II;
  float acc[RR];
#pragma unroll
  for (int r = 0; r < RR; ++r) acc[r] = 0.f;
#pragma unroll
  for (int c = 0; c < II / 512; ++c) {
    const uint4 v = *(const uint4*)(hrow + c * 512 + lane * 8);
    float xv[8];
    xv[0] = __uint_as_float(v.x << 16); xv[1] = __uint_as_float(v.x & 0xffff0000u);
    xv[2] = __uint_as_float(v.y << 16); xv[3] = __uint_as_float(v.y & 0xffff0000u);
    xv[4] = __uint_as_float(v.z << 16); xv[5] = __uint_as_float(v.z & 0xffff0000u);
    xv[6] = __uint_as_float(v.w << 16); xv[7] = __uint_as_float(v.w & 0xffff0000u);
#pragma unroll
    for (int r = 0; r < RR; ++r) {
      const float4 a0 = *(const float4*)(A + (size_t)r * II + c * 512 + lane * 8);
      const float4 a1 = *(const float4*)(A + (size_t)r * II + c * 512 + lane * 8 + 4);
      acc[r] += xv[0] * a0.x + xv[1] * a0.y + xv[2] * a0.z + xv[3] * a0.w +
                xv[4] * a1.x + xv[5] * a1.y + xv[6] * a1.z + xv[7] * a1.w;
    }
  }
#pragma unroll
  for (int r = 0; r < RR; ++r) {
    float v = acc[r];
#pragma unroll
    for (int off = 32; off > 0; off >>= 1) v += __shfl_down(v, off, 64);
    if (lane == 0) ha[(size_t)t * RR + r] = v;
  }
}

// ---------------- gemm1: 128x128, BK=64, 4 waves, 1 compute phase/tile ------
// B panel = 128 WguT rows = 64 hidden cols (16-granular gate/up interleave).
// Wave wc owns B rows [wc*64, wc*64+64): n-frag parity = gate/up; pairs
// (2f,2f+1) share hidden-col block it*4 + wc*2 + f. acc[4][4]=64 f32/thread.
__global__ __launch_bounds__(256) void gemm1_8p_kernel(
    const unsigned short* __restrict__ xb, const unsigned short* __restrict__ WguT,
    const float* __restrict__ xa, const float* __restrict__ Bgu,
    unsigned short* __restrict__ hidden) {
  __shared__ unsigned short sm[2][16384];  // A 128x64 @0, B 128x64 @byte16384; 64KB

  const int bid = blockIdx.x;          // 2048 = 8e * 8tt * 32it (swizzled)
  const int e = bid & 7;
  const int s = bid >> 3;              // 0..255
  const int g = s >> 6, wq = s & 63;   // groups of {8tt x 8it} = 4MB L2 set
  const int tt = wq >> 3, it = (g << 3) | (wq & 7);
  const int t0 = e * TT + tt * 128;
  const unsigned short* Ag = xb + (size_t)t0 * HH;
  const unsigned short* Bg = WguT + (size_t)e * FF2 * HH + (size_t)(it * 128) * HH;

  const int tid = threadIdx.x;
  const int w = tid >> 6, lane = tid & 63;
  const int wr = w >> 1, wc = w & 1;
  const int lrow = lane & 15, lkg = lane >> 4;

  auto stageA = [&](int buf, int kt, int h) {
#pragma unroll
    for (int l = 0; l < 2; ++l) {
      const int i = tid + l * 256;
      const int r = i >> 3, sl = i & 7;
      const int row = h * 64 + r;
      GLOAD16((const char*)(Ag + (size_t)row * HH + kt * 64 + ((sl ^ (row & 7)) << 3)),
              (char*)&sm[buf][0] + row * 128 + sl * 16);
    }
  };
  auto stageB = [&](int buf, int kt, int h) {
#pragma unroll
    for (int l = 0; l < 2; ++l) {
      const int i = tid + l * 256;
      const int r = i >> 3, sl = i & 7;
      const int row = h * 64 + r;
      GLOAD16((const char*)(Bg + (size_t)row * HH + kt * 64 + ((sl ^ (row & 7)) << 3)),
              (char*)&sm[buf][0] + 16384 + row * 128 + sl * 16);
    }
  };
  auto ldA = [&](int p, int mIdx, int s2) -> bf16x8 {
    const int row = wr * 64 + mIdx * 16 + lrow;
    const int sl = (s2 * 4 + lkg) ^ (row & 7);
    return *(const bf16x8*)((const char*)&sm[p][0] + row * 128 + sl * 16);
  };
  auto ldB = [&](int p, int nj, int s2) -> bf16x8 {
    const int row = wc * 64 + nj * 16 + lrow;
    const int sl = (s2 * 4 + lkg) ^ (row & 7);
    return *(const bf16x8*)((const char*)&sm[p][0] + 16384 + row * 128 + sl * 16);
  };

  f32x4 acc[4][4];
#pragma unroll
  for (int i = 0; i < 4; ++i)
#pragma unroll
    for (int j = 0; j < 4; ++j) acc[i][j] = (f32x4)(0.f);

  stageA(0, 0, 0); stageA(0, 0, 1); stageB(0, 0, 0); stageB(0, 0, 1);

  const int NT = HH / 64;  // 16
  for (int t = 0; t < NT; ++t) {
    const int p = t & 1, q = p ^ 1;
    if (t + 1 < NT) {
      stageA(q, t + 1, 0); stageA(q, t + 1, 1);
      stageB(q, t + 1, 0); stageB(q, t + 1, 1);
      WAITV8;
    } else {
      WAITV0;
    }
    BARRIER;
    bf16x8 af[4][2], bfr[4][2];
#pragma unroll
    for (int mi = 0; mi < 4; ++mi) { af[mi][0] = ldA(p, mi, 0); af[mi][1] = ldA(p, mi, 1); }
#pragma unroll
    for (int nj = 0; nj < 4; ++nj) { bfr[nj][0] = ldB(p, nj, 0); bfr[nj][1] = ldB(p, nj, 1); }
#pragma unroll
    for (int mi = 0; mi < 4; ++mi)
#pragma unroll
      for (int nj = 0; nj < 4; ++nj)
#pragma unroll
        for (int s2 = 0; s2 < 2; ++s2)
          acc[mi][nj] = __builtin_amdgcn_mfma_f32_16x16x32_bf16(af[mi][s2], bfr[nj][s2], acc[mi][nj], 0, 0, 0);
    CFENCE;
    BARRIER;
  }

  // epilogue: LoRA + SwiGLU, bf16 store. n-frag pairs (2f, 2f+1) = (gate, up)
  // for hidden col block it*4 + wc*2 + f.
  const float4* xa4 = (const float4*)xa;
  const float4* B4 = (const float4*)Bgu;
#pragma unroll
  for (int f = 0; f < 2; ++f) {
    const int gc = it * 64 + (wc * 2 + f) * 16 + lrow;
    const float4 bg0 = B4[gc * 2], bg1 = B4[gc * 2 + 1];
    const float4 bu0 = B4[(II + gc) * 2], bu1 = B4[(II + gc) * 2 + 1];
#pragma unroll
    for (int m = 0; m < 4; ++m) {
      const int tb = t0 + wr * 64 + m * 16 + lkg * 4;
#pragma unroll
      for (int j = 0; j < 4; ++j) {
        const int trow = tb + j;
        const float4 xr0 = xa4[trow * 2], xr1 = xa4[trow * 2 + 1];
        const float gv = acc[m][f * 2 + 0][j] + SCAL * (dot4(xr0, bg0) + dot4(xr1, bg1));
        const float uv = acc[m][f * 2 + 1][j] + SCAL * (dot4(xr0, bu0) + dot4(xr1, bu1));
        const float sg = gv / (1.f + __expf(-gv));
        hidden[(size_t)trow * II + gc] = f2bf(uv * sg);
      }
    }
  }
}

// ---------------- gemm2: 128x128, BK=64, 4 waves, 1 compute phase/tile ------
__global__ __launch_bounds__(256) void gemm2_8p_kernel(
    const unsigned short* __restrict__ hid, const unsigned short* __restrict__ WdnT,
    const float* __restrict__ ha, const float* __restrict__ Bdn,
    float* __restrict__ out) {
  __shared__ unsigned short sm[2][16384];  // A 128x64 @0, B 128x64 @byte16384; 64KB

  const int bid = blockIdx.x;          // 512 = 8e * 8tt * 8ht (swizzled)
  const int e = bid & 7;
  const int s = bid >> 3;              // 0..63
  const int g = s >> 4, wq = s & 15;   // groups of {4tt x 4ht} = 4MB L2 set
  const int tt = (g >> 1) * 4 + (wq >> 2);
  const int ht = (g & 1) * 4 + (wq & 3);
  const int t0 = e * TT + tt * 128;
  const int h0 = ht * 128;
  const unsigned short* Ag = hid + (size_t)t0 * II;
  const unsigned short* Bg = WdnT + (size_t)e * HH * II + (size_t)h0 * II;

  const int tid = threadIdx.x;
  const int w = tid >> 6, lane = tid & 63;
  const int wr = w >> 1, wc = w & 1;
  const int lrow = lane & 15, lkg = lane >> 4;

  auto stageA = [&](int buf, int kt, int h) {
#pragma unroll
    for (int l = 0; l < 2; ++l) {
      const int i = tid + l * 256;
      const int r = i >> 3, sl = i & 7;
      const int row = h * 64 + r;
      GLOAD16((const char*)(Ag + (size_t)row * II + kt * 64 + ((sl ^ (row & 7)) << 3)),
              (char*)&sm[buf][0] + row * 128 + sl * 16);
    }
  };
  auto stageB = [&](int buf, int kt, int h) {
#pragma unroll
    for (int l = 0; l < 2; ++l) {
      const int i = tid + l * 256;
      const int r = i >> 3, sl = i & 7;
      const int row = h * 64 + r;
      GLOAD16((const char*)(Bg + (size_t)row * II + kt * 64 + ((sl ^ (row & 7)) << 3)),
              (char*)&sm[buf][0] + 16384 + row * 128 + sl * 16);
    }
  };
  auto ldA = [&](int p, int mIdx, int s2) -> bf16x8 {
    const int row = wr * 64 + mIdx * 16 + lrow;
    const int sl = (s2 * 4 + lkg) ^ (row & 7);
    return *(const bf16x8*)((const char*)&sm[p][0] + row * 128 + sl * 16);
  };
  auto ldB = [&](int p, int nj, int s2) -> bf16x8 {
    const int row = wc * 64 + nj * 16 + lrow;
    const int sl = (s2 * 4 + lkg) ^ (row & 7);
    return *(const bf16x8*)((const char*)&sm[p][0] + 16384 + row * 128 + sl * 16);
  };

  f32x4 acc[4][4];
#pragma unroll
  for (int i = 0; i < 4; ++i)
#pragma unroll
    for (int j = 0; j < 4; ++j) acc[i][j] = (f32x4)(0.f);

  stageA(0, 0, 0); stageA(0, 0, 1); stageB(0, 0, 0); stageB(0, 0, 1);

  const int NT = II / 64;  // 32
  for (int t = 0; t < NT; ++t) {
    const int p = t & 1, q = p ^ 1;
    if (t + 1 < NT) {
      stageA(q, t + 1, 0); stageA(q, t + 1, 1);
      stageB(q, t + 1, 0); stageB(q, t + 1, 1);
      WAITV8;
    } else {
      WAITV0;
    }
    BARRIER;
    bf16x8 af[4][2], bfr[4][2];
#pragma unroll
    for (int mi = 0; mi < 4; ++mi) { af[mi][0] = ldA(p, mi, 0); af[mi][1] = ldA(p, mi, 1); }
#pragma unroll
    for (int nj = 0; nj < 4; ++nj) { bfr[nj][0] = ldB(p, nj, 0); bfr[nj][1] = ldB(p, nj, 1); }
#pragma unroll
    for (int mi = 0; mi < 4; ++mi)
#pragma unroll
      for (int nj = 0; nj < 4; ++nj)
#pragma unroll
        for (int s2 = 0; s2 < 2; ++s2)
          acc[mi][nj] = __builtin_amdgcn_mfma_f32_16x16x32_bf16(af[mi][s2], bfr[nj][s2], acc[mi][nj], 0, 0, 0);
    CFENCE;
    BARRIER;
  }

  const float4* ha4 = (const float4*)ha;
  const float4* B4 = (const float4*)Bdn;
#pragma unroll
  for (int nj = 0; nj < 4; ++nj) {
    const int col = h0 + wc * 64 + nj * 16 + lrow;
    const float4 b0 = B4[col * 2], b1 = B4[col * 2 + 1];
#pragma unroll
    for (int m = 0; m < 4; ++m) {
      const int tb = t0 + wr * 64 + m * 16 + lkg * 4;
#pragma unroll
      for (int j = 0; j < 4; ++j) {
        const int trow = tb + j;
        const float4 hr0 = ha4[trow * 2], hr1 = ha4[trow * 2 + 1];
        out[(size_t)trow * HH + col] = acc[m][nj][j] + SCAL * (dot4(hr0, b0) + dot4(hr1, b1));
      }
    }
  }
}

// ---------------- fallback (R3): in-loop conversion GEMMs -------------------
__global__ __launch_bounds__(256) void gemm1_conv_kernel(const float* __restrict__ x,
                                                         const float* __restrict__ Wgu,
                                                         const float* __restrict__ xa,
                                                         const float* __restrict__ Bgu,
                                                         unsigned short* __restrict__ hidden) {
  __shared__ unsigned short As[128][40];
  __shared__ unsigned short Bs[128][40];
  const int bid = blockIdx.x;
  const int e = bid >> 8, rem = bid & 255, tt = rem >> 5, it = rem & 31;
  const int t0 = e * TT + tt * 128, i0 = it * 64;
  const float* Wg = Wgu + (size_t)e * HH * FF2;
  const int tid = threadIdx.x, w = tid >> 6, lane = tid & 63;
  const int wr = w >> 1, wc = w & 1, lrow = lane & 15, lk = (lane >> 4) * 8;
  f32x4 acc[4][4];
#pragma unroll
  for (int i = 0; i < 4; ++i)
#pragma unroll
    for (int j = 0; j < 4; ++j) acc[i][j] = (f32x4)(0.f);
  for (int k0 = 0; k0 < HH; k0 += 32) {
#pragma unroll
    for (int l = 0; l < 4; ++l) {
      const int idx = tid + l * 256, row = idx >> 3, kq = idx & 7;
      const float4 v = *(const float4*)(x + (size_t)(t0 + row) * HH + k0 + kq * 4);
      ushort4 p; p.x = f2bf(v.x); p.y = f2bf(v.y); p.z = f2bf(v.z); p.w = f2bf(v.w);
      *(ushort4*)&As[row][kq * 4] = p;
    }
#pragma unroll
    for (int l = 0; l < 2; ++l) {
      const int idx = tid + l * 256, col = idx & 127, kq8 = idx >> 7;
      const int gcol = i0 + (col & 63) + ((col >> 6) * II);
      union { unsigned short u[8]; uint4 v; } pk;
#pragma unroll
      for (int kk = 0; kk < 8; ++kk) pk.u[kk] = f2bf(Wg[(size_t)(k0 + kq8 * 8 + kk) * FF2 + gcol]);
      *(uint4*)&Bs[col][kq8 * 8] = pk.v;
    }
    __syncthreads();
    bf16x8 af[4], bfr[4];
#pragma unroll
    for (int mi = 0; mi < 4; ++mi) af[mi] = *(const bf16x8*)&As[wr * 64 + mi * 16 + lrow][lk];
#pragma unroll
    for (int nj = 0; nj < 4; ++nj) {
      const int c = (nj < 2) ? (wc * 32 + nj * 16) : (64 + wc * 32 + (nj - 2) * 16);
      bfr[nj] = *(const bf16x8*)&Bs[c + lrow][lk];
    }
#pragma unroll
    for (int mi = 0; mi < 4; ++mi)
#pragma unroll
      for (int nj = 0; nj < 4; ++nj)
        acc[mi][nj] = __builtin_amdgcn_mfma_f32_16x16x32_bf16(af[mi], bfr[nj], acc[mi][nj], 0, 0, 0);
    __syncthreads();
  }
  const float4* xa4 = (const float4*)xa;
  const float4* B4 = (const float4*)Bgu;
#pragma unroll
  for (int nj = 0; nj < 2; ++nj) {
    const int coln = i0 + wc * 32 + nj * 16 + lrow;
    const float4 bg0 = B4[coln * 2], bg1 = B4[coln * 2 + 1];
    const float4 bu0 = B4[(II + coln) * 2], bu1 = B4[(II + coln) * 2 + 1];
#pragma unroll
    for (int mi = 0; mi < 4; ++mi) {
      const int tb = t0 + wr * 64 + mi * 16 + (lane >> 4) * 4;
#pragma unroll
      for (int j = 0; j < 4; ++j) {
        const int t = tb + j;
        const float4 xr0 = xa4[t * 2], xr1 = xa4[t * 2 + 1];
        const float g = acc[mi][nj][j] + SCAL * (dot4(xr0, bg0) + dot4(xr1, bg1));
        const float u = acc[mi][nj + 2][j] + SCAL * (dot4(xr0, bu0) + dot4(xr1, bu1));
        const float s = g / (1.f + __expf(-g));
        hidden[(size_t)t * II + coln] = f2bf(u * s);
      }
    }
  }
}

__global__ __launch_bounds__(256) void gemm2_conv_kernel(const unsigned short* __restrict__ hid,
                                                         const float* __restrict__ Wdn,
                                                         const float* __restrict__ ha,
                                                         const float* __restrict__ Bdn,
                                                         float* __restrict__ out) {
  __shared__ unsigned short As[128][40];
  __shared__ unsigned short Bs[128][40];
  const int bid = blockIdx.x;
  const int e = bid >> 6, rem = bid & 63, tt = rem >> 3, ht = rem & 7;
  const int t0 = e * TT + tt * 128, h0 = ht * 128;
  const float* Wd = Wdn + (size_t)e * II * HH;
  const int tid = threadIdx.x, w = tid >> 6, lane = tid & 63;
  const int wr = w >> 1, wc = w & 1, lrow = lane & 15, lk = (lane >> 4) * 8;
  f32x4 acc[4][4];
#pragma unroll
  for (int i = 0; i < 4; ++i)
#pragma unroll
    for (int j = 0; j < 4; ++j) acc[i][j] = (f32x4)(0.f);
  for (int k0 = 0; k0 < II; k0 += 32) {
#pragma unroll
    for (int l = 0; l < 2; ++l) {
      const int idx = tid + l * 256, row = idx >> 2, kq8 = idx & 3;
      *(uint4*)&As[row][kq8 * 8] = *(const uint4*)(hid + (size_t)(t0 + row) * II + k0 + kq8 * 8);
    }
#pragma unroll
    for (int l = 0; l < 2; ++l) {
      const int idx = tid + l * 256, col = idx & 127, kq8 = idx >> 7;
      union { unsigned short u[8]; uint4 v; } pk;
#pragma unroll
      for (int kk = 0; kk < 8; ++kk) pk.u[kk] = f2bf(Wd[(size_t)(k0 + kq8 * 8 + kk) * HH + h0 + col]);
      *(uint4*)&Bs[col][kq8 * 8] = pk.v;
    }
    __syncthreads();
    bf16x8 af[4], bfr[4];
#pragma unroll
    for (int mi = 0; mi < 4; ++mi) af[mi] = *(const bf16x8*)&As[wr * 64 + mi * 16 + lrow][lk];
#pragma unroll
    for (int nj = 0; nj < 4; ++nj) bfr[nj] = *(const bf16x8*)&Bs[wc * 64 + nj * 16 + lrow][lk];
#pragma unroll
    for (int mi = 0; mi < 4; ++mi)
#pragma unroll
      for (int nj = 0; nj < 4; ++nj)
        acc[mi][nj] = __builtin_amdgcn_mfma_f32_16x16x32_bf16(af[mi], bfr[nj], acc[mi][nj], 0, 0, 0);
    __syncthreads();
  }
  const float4* ha4 = (const float4*)ha;
  const float4* B4 = (const float4*)Bdn;
#pragma unroll
  for (int nj = 0; nj < 4; ++nj) {
    const int coln = h0 + wc * 64 + nj * 16 + lrow;
    const float4 b0 = B4[coln * 2], b1 = B4[coln * 2 + 1];
#pragma unroll
    for (int mi = 0; mi < 4; ++mi) {
      const int tb = t0 + wr * 64 + mi * 16 + (lane >> 4) * 4;
#pragma unroll
      for (int j = 0; j < 4; ++j) {
        const int t = tb + j;
        const float4 hr0 = ha4[t * 2], hr1 = ha4[t * 2 + 1];
        out[(size_t)t * HH + coln] = acc[mi][nj][j] + SCAL * (dot4(hr0, b0) + dot4(hr1, b1));
      }
    }
  }
}

extern "C" void kernel_launch(void* const* d_in, const int* in_sizes, int n_in,
                              void* d_out, int out_size, void* d_ws, size_t ws_size,
                              hipStream_t stream) {
  const float* x   = (const float*)d_in[0];
  const float* Wgu = (const float*)d_in[1];
  const float* Wdn = (const float*)d_in[2];
  const float* Agu = (const float*)d_in[3];
  const float* Bgu = (const float*)d_in[4];
  const float* Adn = (const float*)d_in[5];
  const float* Bdn = (const float*)d_in[6];
  float* out = (float*)d_out;

  char* ws = (char*)d_ws;
  unsigned short* hidden = (unsigned short*)ws;                      //  32 MB
  const size_t OFF_XB  = (size_t)NROW * II * 2;                      //  32 MB
  const size_t OFF_WGU = OFF_XB + (size_t)NROW * HH * 2;             //  48 MB
  const size_t OFF_WDN = OFF_WGU + (size_t)NE * FF2 * HH * 2;        // 112 MB
  const size_t OFF_XA  = OFF_WDN + (size_t)NE * HH * II * 2;         // 144 MB
  const size_t OFF_HA  = OFF_XA + (size_t)NROW * RR * 4;
  const size_t NEED    = OFF_HA + (size_t)NROW * RR * 4;

  if (ws_size >= NEED) {
    unsigned short* xb   = (unsigned short*)(ws + OFF_XB);
    unsigned short* WguT = (unsigned short*)(ws + OFF_WGU);
    unsigned short* WdnT = (unsigned short*)(ws + OFF_WDN);
    float* xa = (float*)(ws + OFF_XA);
    float* ha = (float*)(ws + OFF_HA);

    convx_kernel<<<(NROW * HH) / (256 * 8), 256, 0, stream>>>(x, xb);
    transconv_gu_kernel<<<NE * 16 * 64, 256, 0, stream>>>(Wgu, WguT);
    transconv_dn_kernel<<<NE * 32 * 16, 256, 0, stream>>>(Wdn, WdnT);
    rowdot_kernel<HH><<<NROW / 4, 256, 0, stream>>>(x, Agu, xa);
    gemm1_8p_kernel<<<NE * 8 * 32, 256, 0, stream>>>(xb, WguT, xa, Bgu, hidden);
    rowdot_bf16_kernel<<<NROW / 4, 256, 0, stream>>>(hidden, Adn, ha);
    gemm2_8p_kernel<<<NE * 8 * 8, 256, 0, stream>>>(hidden, WdnT, ha, Bdn, out);
  } else {
    float* xa = (float*)(ws + OFF_XB);
    float* ha = xa + (size_t)NROW * RR;
    rowdot_kernel<HH><<<NROW / 4, 256, 0, stream>>>(x, Agu, xa);
    gemm1_conv_kernel<<<NE * 8 * 32, 256, 0, stream>>>(x, Wgu, xa, Bgu, hidden);
    rowdot_bf16_kernel<<<NROW / 4, 256, 0, stream>>>(hidden, Adn, ha);
    gemm2_conv_kernel<<<NE * 8 * 8, 256, 0, stream>>>(hidden, Wdn, ha, Bdn, out);
  }
}